// Round 7
// baseline (436.499 us; speedup 1.0000x reference)
//
#include <hip/hip_runtime.h>
#include <hip/hip_bf16.h>
#include <cmath>
#include <cstdint>

typedef __bf16 bf16;
typedef __bf16 bf16x8 __attribute__((ext_vector_type(8)));
typedef __bf16 bf16x4 __attribute__((ext_vector_type(4)));
typedef float  f32x4  __attribute__((ext_vector_type(4)));

#define EMBED 1024
#define FFDIM 4096
#define BATCH 4
#define SEQ   2048
#define MTOK  (BATCH*SEQ)

// ---------------- workspace layout ----------------
static constexpr size_t OFF_XPE_F32 = 0;              // 32MB f32 (live until LN1)
static constexpr size_t OFF_XPE_B   = 32ull << 20;    // 16MB bf16; reused as h_bf16
static constexpr size_t OFF_Q       = 48ull << 20;    // 16MB bf16; Q..K reused as P (32MB); then FF2 part1
static constexpr size_t OFF_K       = 64ull << 20;    // 16MB bf16
static constexpr size_t OFF_VT      = 80ull << 20;    // 16MB bf16 [4][1024][2048]
static constexpr size_t OFF_E       = 96ull << 20;    // 64MB f32 E; then PV part1 (32MB); then T1 bf16
static constexpr size_t OFF_ATTN    = 160ull << 20;   // 32MB f32: PV part0; then FF2 part0
static constexpr size_t OFF_H       = 192ull << 20;   // 32MB f32 h
static constexpr size_t OFF_WQKVT   = 224ull << 20;   // 6MB bf16 [3072][1024]
static constexpr size_t OFF_W1T     = 230ull << 20;   // 8MB
static constexpr size_t OFF_W2T     = 238ull << 20;   // 8MB

// ---------------- wait/barrier primitives ----------------
#define VMCNT0 { asm volatile("s_waitcnt vmcnt(0)" ::: "memory"); __builtin_amdgcn_sched_barrier(0); }
#define BARRAW { asm volatile("s_waitcnt lgkmcnt(0)" ::: "memory"); __builtin_amdgcn_s_barrier(); __builtin_amdgcn_sched_barrier(0); }

__device__ __forceinline__ void gload_lds16(const void* g, void* l) {
  __builtin_amdgcn_global_load_lds((const __attribute__((address_space(1))) void*)g,
                                   (__attribute__((address_space(3))) void*)l, 16, 0, 0);
}

// ---------------- PE add ----------------
__global__ __launch_bounds__(256) void pe_add_kernel(const float* __restrict__ x,
                                                     float* __restrict__ xf,
                                                     bf16* __restrict__ xb) {
  int idx  = blockIdx.x * 256 + threadIdx.x;
  int pair = idx & 511;
  int s    = idx >> 9;
  float div = __expf((float)(2 * pair) * (-9.210340371976184f / (float)EMBED));
  float ang = (float)s * div;
  float sv = sinf(ang), cv = cosf(ang);
#pragma unroll
  for (int b = 0; b < BATCH; ++b) {
    size_t base = ((size_t)(b * SEQ + s)) * EMBED + (size_t)pair * 2;
    float v0 = x[base] + sv;
    float v1 = x[base + 1] + cv;
    xf[base] = v0; xf[base + 1] = v1;
    xb[base] = (bf16)v0; xb[base + 1] = (bf16)v1;
  }
}

// ---------------- weight transpose fp32[K][N] -> bf16[N][K] ----------------
__global__ __launch_bounds__(256) void transpose_kernel(const float* __restrict__ W,
                                                        bf16* __restrict__ Wt,
                                                        int K, int N) {
  __shared__ float tile[32][33];
  int nb = blockIdx.x * 32, kb = blockIdx.y * 32;
  int tx = threadIdx.x, ty = threadIdx.y;   // 32x8
#pragma unroll
  for (int i = 0; i < 32; i += 8)
    tile[ty + i][tx] = W[(size_t)(kb + ty + i) * N + nb + tx];
  __syncthreads();
#pragma unroll
  for (int i = 0; i < 32; i += 8)
    Wt[(size_t)(nb + ty + i) * K + kb + tx] = (bf16)tile[tx][ty + i];
}

// ---------------- gemmx: 256x256 tile, 8 waves (2Mx4N), wave-out 128x64 ----------------
// dbuf 128KB LDS; stage ALL of tile T+1 before computing tile T; one vmcnt(0)+barrier
// per tile. lda/ldb are row strides (elements); K is reduction extent only.
// EPI 2: f32 out, *scale (QK^T / PV / FF2-split)
// EPI 3: bf16 out, +bias, relu (FF1)
// EPI 6: fused QKV (Q,K row-major bf16 +bias; V scatter->VT)
#define BMX 256
#define BNX 256
#define BKX 64

template <int EPI>
__global__ __launch_bounds__(512, 2) void gemmx_kernel(
    const bf16* __restrict__ A, const bf16* __restrict__ B,
    const float* __restrict__ bias, void* __restrict__ out,
    int K, int lda, int ldb, int ldo, int NB,
    long long sAz, long long sBz, long long sOz,
    long long sAk, long long sBk, long long sOk,
    float scale,
    const float* bias2, const float* bias3, void* out2, void* out3) {
  __shared__ __align__(16) bf16 sA[2][BMX][BKX];   // 2 x 32KB
  __shared__ __align__(16) bf16 sB[2][BNX][BKX];   // 2 x 32KB

  // bijective XCD-chunked swizzle (m204) + grouped raster (G=8)
  const int gx = gridDim.x, gy = gridDim.y;
  int id = blockIdx.x + gx * (blockIdx.y + gy * blockIdx.z);
  const int nwg = gx * gy * gridDim.z;
  const int qd = nwg >> 3, rm = nwg & 7;
  const int xcd = id & 7, pos = id >> 3;
  const int lid = (xcd < rm ? xcd * (qd + 1) : rm * (qd + 1) + (xcd - rm) * qd) + pos;
  const int per = gx * gy;
  const int tz = lid / per;
  const int s2 = lid - tz * per;
  const int G = 8;
  const int ngrp = G * gy;
  const int grp = s2 / ngrp;
  const int within = s2 - grp * ngrp;
  const int gwf = gx - grp * G;
  const int gw = gwf < G ? gwf : G;
  const int tx = grp * G + within % gw;
  const int ty = within / gw;

  const int zb = tz % NB;        // batch index
  const int kh = tz / NB;        // K-split index
  A += (long long)zb * sAz + (long long)kh * sAk;
  B += (long long)zb * sBz + (long long)kh * sBk;

  const int tid  = threadIdx.x;
  const int wave = tid >> 6;
  const int lane = tid & 63;
  const int wm = wave >> 2, wn = wave & 3;   // 2M x 4N
  const int rowBase = ty * BMX;
  const int colBase = tx * BNX;

  // staging: thread t covers row i*64 + (t>>3), slot t&7 (src XOR-swizzled by row&7)
  const int rS = tid >> 3;
  const int srcSlot = (tid & 7) ^ (rS & 7);
  const bf16* gA = A + (long long)(rowBase + rS) * lda + srcSlot * 8;
  const bf16* gB = B + (long long)(colBase + rS) * ldb + srcSlot * 8;

  auto stage = [&](int buf, int T) {
    char* dA = (char*)&sA[buf][0][0] + wave * 1024;
    char* dB = (char*)&sB[buf][0][0] + wave * 1024;
    const bf16* srcA = gA + (size_t)T * BKX;
    const bf16* srcB = gB + (size_t)T * BKX;
#pragma unroll
    for (int i = 0; i < 4; ++i) {
      gload_lds16(srcA + (long long)(i * 64) * lda, dA + i * 8192);
      gload_lds16(srcB + (long long)(i * 64) * ldb, dB + i * 8192);
    }
  };

  const f32x4 zero4 = {0.f, 0.f, 0.f, 0.f};
  f32x4 acc[8][4];
#pragma unroll
  for (int i = 0; i < 8; ++i)
#pragma unroll
    for (int j = 0; j < 4; ++j) acc[i][j] = zero4;

  const int lr = lane & 15;
  const int g  = lane >> 4;
  const int nK = K / BKX;

  stage(0, 0);
  VMCNT0; BARRAW;

  int cur = 0;
  for (int T = 0; T < nK; ++T) {
    if (T + 1 < nK) stage(cur ^ 1, T + 1);
    __builtin_amdgcn_sched_barrier(0);

    const char* cA = (const char*)&sA[cur][0][0] + wm * (128 * 128);
    const char* cB = (const char*)&sB[cur][0][0] + wn * (64 * 128);
#pragma unroll
    for (int kk = 0; kk < 2; ++kk) {
      bf16x8 fa[8], fb[4];
      const int sw = ((kk * 4 + g) ^ (lr & 7)) << 4;
#pragma unroll
      for (int i = 0; i < 8; ++i)
        fa[i] = *(const bf16x8*)(cA + (i * 16 + lr) * 128 + sw);
#pragma unroll
      for (int j = 0; j < 4; ++j)
        fb[j] = *(const bf16x8*)(cB + (j * 16 + lr) * 128 + sw);
      __builtin_amdgcn_s_setprio(1);
#pragma unroll
      for (int i = 0; i < 8; ++i)
#pragma unroll
        for (int j = 0; j < 4; ++j)
          acc[i][j] = __builtin_amdgcn_mfma_f32_16x16x32_bf16(fa[i], fb[j], acc[i][j], 0, 0, 0);
      __builtin_amdgcn_s_setprio(0);
    }

    VMCNT0; BARRAW;
    cur ^= 1;
  }

  // epilogue: C/D layout col = lane&15, row = (lane>>4)*4 + reg  [m89-verified]
#pragma unroll
  for (int j = 0; j < 4; ++j) {
    const int col = colBase + wn * 64 + j * 16 + lr;
#pragma unroll
    for (int i = 0; i < 8; ++i) {
      const int row0 = rowBase + wm * 128 + i * 16 + g * 4;
      if constexpr (EPI == 6) {
        const int cb = col >> 10;         // uniform per block (colBase mult of 256)
        const int c  = col & 1023;
        const float bv = (cb == 0 ? bias : (cb == 1 ? bias2 : bias3))[c];
        if (cb == 2) {
          const int b_ = row0 >> 11;
          const int s_ = row0 & (SEQ - 1);
          bf16x4 pv;
#pragma unroll
          for (int rr = 0; rr < 4; ++rr) pv[rr] = (bf16)(acc[i][j][rr] + bv);
          *(bf16x4*)((bf16*)out3 + ((size_t)b_ * EMBED + c) * SEQ + s_) = pv;
        } else {
          bf16* dst = (cb == 0 ? (bf16*)out : (bf16*)out2);
#pragma unroll
          for (int rr = 0; rr < 4; ++rr)
            dst[(size_t)(row0 + rr) * EMBED + c] = (bf16)(acc[i][j][rr] + bv);
        }
      } else if constexpr (EPI == 2) {
        float* dst = (float*)out + (long long)zb * sOz + (long long)kh * sOk;
#pragma unroll
        for (int rr = 0; rr < 4; ++rr)
          dst[(long long)(row0 + rr) * ldo + col] = acc[i][j][rr] * scale;
      } else if constexpr (EPI == 3) {
        const float bv = bias[col];
#pragma unroll
        for (int rr = 0; rr < 4; ++rr) {
          float t = acc[i][j][rr] + bv;
          ((bf16*)out)[(size_t)(row0 + rr) * ldo + col] = (bf16)(t > 0.f ? t : 0.f);
        }
      }
    }
  }
}

// ---------------- row softmax: E f32 [rows][SEQ] -> P bf16 ----------------
__global__ __launch_bounds__(256) void softmax_kernel(const float* __restrict__ E,
                                                      bf16* __restrict__ P) {
  const size_t row = blockIdx.x;
  const float* e = E + row * SEQ;
  const int t = threadIdx.x;
  float4 a = ((const float4*)e)[2 * t];
  float4 b = ((const float4*)e)[2 * t + 1];
  float m = fmaxf(fmaxf(fmaxf(a.x, a.y), fmaxf(a.z, a.w)),
                  fmaxf(fmaxf(b.x, b.y), fmaxf(b.z, b.w)));
#pragma unroll
  for (int o = 32; o; o >>= 1) m = fmaxf(m, __shfl_xor(m, o));
  __shared__ float red[8];
  const int w = t >> 6;
  if ((t & 63) == 0) red[w] = m;
  __syncthreads();
  m = fmaxf(fmaxf(red[0], red[1]), fmaxf(red[2], red[3]));
  float ex[8];
  ex[0] = __expf(a.x - m); ex[1] = __expf(a.y - m);
  ex[2] = __expf(a.z - m); ex[3] = __expf(a.w - m);
  ex[4] = __expf(b.x - m); ex[5] = __expf(b.y - m);
  ex[6] = __expf(b.z - m); ex[7] = __expf(b.w - m);
  float s = ex[0] + ex[1] + ex[2] + ex[3] + ex[4] + ex[5] + ex[6] + ex[7];
#pragma unroll
  for (int o = 32; o; o >>= 1) s += __shfl_xor(s, o);
  if ((t & 63) == 0) red[4 + w] = s;
  __syncthreads();
  s = red[4] + red[5] + red[6] + red[7];
  const float inv = 1.0f / s;
  bf16x8 pv;
#pragma unroll
  for (int q = 0; q < 8; ++q) pv[q] = (bf16)(ex[q] * inv);
  *(bf16x8*)(P + row * SEQ + (size_t)t * 8) = pv;
}

// ---------------- LayerNorm: out = LN(X [+X2] [+cb] + R) * g + b ----------------
__global__ __launch_bounds__(256) void ln_kernel(const float* __restrict__ X,
                                                 const float* __restrict__ X2,
                                                 const float* __restrict__ R,
                                                 const float* __restrict__ cb,
                                                 const float* __restrict__ gm,
                                                 const float* __restrict__ bt,
                                                 float* __restrict__ of,
                                                 bf16* __restrict__ ob) {
  const size_t row = blockIdx.x;
  const int t = threadIdx.x;
  float4 xv = ((const float4*)(X + row * EMBED))[t];
  float4 rv = ((const float4*)(R + row * EMBED))[t];
  float4 v;
  v.x = xv.x + rv.x; v.y = xv.y + rv.y; v.z = xv.z + rv.z; v.w = xv.w + rv.w;
  if (X2) {
    float4 x2 = ((const float4*)(X2 + row * EMBED))[t];
    v.x += x2.x; v.y += x2.y; v.z += x2.z; v.w += x2.w;
  }
  if (cb) {
    float4 c4 = ((const float4*)cb)[t];
    v.x += c4.x; v.y += c4.y; v.z += c4.z; v.w += c4.w;
  }
  float s  = v.x + v.y + v.z + v.w;
  float ss = v.x * v.x + v.y * v.y + v.z * v.z + v.w * v.w;
#pragma unroll
  for (int o = 32; o; o >>= 1) { s += __shfl_xor(s, o); ss += __shfl_xor(ss, o); }
  __shared__ float red[8];
  const int w = t >> 6;
  if ((t & 63) == 0) { red[w] = s; red[4 + w] = ss; }
  __syncthreads();
  s  = red[0] + red[1] + red[2] + red[3];
  ss = red[4] + red[5] + red[6] + red[7];
  const float mu  = s * (1.0f / EMBED);
  const float inv = rsqrtf(ss * (1.0f / EMBED) - mu * mu + 1e-5f);
  float4 gv = ((const float4*)gm)[t];
  float4 bv = ((const float4*)bt)[t];
  float4 o4;
  o4.x = (v.x - mu) * inv * gv.x + bv.x;
  o4.y = (v.y - mu) * inv * gv.y + bv.y;
  o4.z = (v.z - mu) * inv * gv.z + bv.z;
  o4.w = (v.w - mu) * inv * gv.w + bv.w;
  if (of) ((float4*)(of + row * EMBED))[t] = o4;
  if (ob) {
    bf16x4 p;
    p[0] = (bf16)o4.x; p[1] = (bf16)o4.y; p[2] = (bf16)o4.z; p[3] = (bf16)o4.w;
    *(bf16x4*)(ob + row * EMBED + (size_t)t * 4) = p;
  }
}

// ---------------- launch ----------------
extern "C" void kernel_launch(void* const* d_in, const int* in_sizes, int n_in,
                              void* d_out, int out_size, void* d_ws, size_t ws_size,
                              hipStream_t stream) {
  const float* x   = (const float*)d_in[0];
  const float* Wq  = (const float*)d_in[1];
  const float* bq  = (const float*)d_in[2];
  const float* Wk  = (const float*)d_in[3];
  const float* bk  = (const float*)d_in[4];
  const float* Wv  = (const float*)d_in[5];
  const float* bv  = (const float*)d_in[6];
  const float* W1  = (const float*)d_in[7];
  const float* b1  = (const float*)d_in[8];
  const float* W2  = (const float*)d_in[9];
  const float* b2  = (const float*)d_in[10];
  const float* g1  = (const float*)d_in[11];
  const float* be1 = (const float*)d_in[12];
  const float* g2  = (const float*)d_in[13];
  const float* be2 = (const float*)d_in[14];
  float* out = (float*)d_out;
  char* ws = (char*)d_ws;

  float* xpe  = (float*)(ws + OFF_XPE_F32);
  bf16*  xpeb = (bf16*)(ws + OFF_XPE_B);
  bf16*  Qb   = (bf16*)(ws + OFF_Q);
  bf16*  Kb   = (bf16*)(ws + OFF_K);
  bf16*  VT   = (bf16*)(ws + OFF_VT);
  float* E    = (float*)(ws + OFF_E);
  bf16*  P    = (bf16*)(ws + OFF_Q);      // reuse Q+K region after QK^T
  float* pv0  = (float*)(ws + OFF_ATTN);  // PV part 0
  bf16*  T1   = (bf16*)(ws + OFF_E);      // FF1 out (E/pv1 dead after LN1)
  float* ff0  = (float*)(ws + OFF_ATTN);  // FF2 part 0 (pv0 dead after LN1)
  float* ff1  = (float*)(ws + OFF_Q);     // FF2 part 1 (P dead after PV)
  float* pv1  = (float*)(ws + OFF_E);     // PV part 1 (E dead after softmax)
  float* h    = (float*)(ws + OFF_H);
  bf16*  hb   = (bf16*)(ws + OFF_XPE_B);  // reuse xpe_bf16 region
  bf16*  WqkvT = (bf16*)(ws + OFF_WQKVT);
  bf16*  W1T  = (bf16*)(ws + OFF_W1T);
  bf16*  W2T  = (bf16*)(ws + OFF_W2T);

  // signed element offsets between split-K output halves
  const long long sOk_pv = (long long)(OFF_E / 4)  - (long long)(OFF_ATTN / 4);   // pv1 - pv0
  const long long sOk_ff = (long long)(OFF_Q / 4)  - (long long)(OFF_ATTN / 4);   // ff1 - ff0

  const dim3 tb(32, 8);
  transpose_kernel<<<dim3(EMBED / 32, EMBED / 32), tb, 0, stream>>>(Wq, WqkvT, EMBED, EMBED);
  transpose_kernel<<<dim3(EMBED / 32, EMBED / 32), tb, 0, stream>>>(Wk, WqkvT + (size_t)EMBED * EMBED, EMBED, EMBED);
  transpose_kernel<<<dim3(EMBED / 32, EMBED / 32), tb, 0, stream>>>(Wv, WqkvT + 2ull * EMBED * EMBED, EMBED, EMBED);
  transpose_kernel<<<dim3(FFDIM / 32, EMBED / 32), tb, 0, stream>>>(W1, W1T, EMBED, FFDIM);
  transpose_kernel<<<dim3(EMBED / 32, FFDIM / 32), tb, 0, stream>>>(W2, W2T, FFDIM, EMBED);

  pe_add_kernel<<<(SEQ * 512) / 256, 256, 0, stream>>>(x, xpe, xpeb);

  // fused QKV: [8192,1024] x [3072,1024]^T -> Q,K row-major; V scatter->VT  (384 blocks)
  gemmx_kernel<6><<<dim3(3072 / BNX, MTOK / BMX, 1), 512, 0, stream>>>(
      xpeb, WqkvT, bq, Qb, EMBED, EMBED, EMBED, EMBED, 1,
      0, 0, 0, 0, 0, 0, 1.0f, bk, bv, Kb, VT);

  // QK^T: E = Q @ K^T / 32  (batched z=4; 256 blocks)
  gemmx_kernel<2><<<dim3(SEQ / BNX, SEQ / BMX, BATCH), 512, 0, stream>>>(
      Qb, Kb, nullptr, E, EMBED, EMBED, EMBED, SEQ, BATCH,
      (long long)SEQ * EMBED, (long long)SEQ * EMBED, (long long)SEQ * SEQ,
      0, 0, 0, 0.03125f, nullptr, nullptr, nullptr, nullptr);

  softmax_kernel<<<BATCH * SEQ, 256, 0, stream>>>(E, P);

  // PV split-K: K=2048 -> 2x1024; z = 4 batches x 2 halves = 8  (256 blocks)
  // lda = ldb = 2048 (P row stride / VT row stride), K = 1024 per half
  gemmx_kernel<2><<<dim3(EMBED / BNX, SEQ / BMX, BATCH * 2), 512, 0, stream>>>(
      P, VT, nullptr, pv0, 1024, SEQ, SEQ, EMBED, BATCH,
      (long long)SEQ * SEQ, (long long)EMBED * SEQ, (long long)SEQ * EMBED,
      1024, 1024, sOk_pv,
      1.0f, nullptr, nullptr, nullptr, nullptr);

  // h = LN(pv0 + pv1 + xpe)
  ln_kernel<<<MTOK, 256, 0, stream>>>(pv0, pv1, xpe, nullptr, g1, be1, h, hb);

  // FF1: relu(h @ W1 + b1)  (512 blocks)
  gemmx_kernel<3><<<dim3(FFDIM / BNX, MTOK / BMX, 1), 512, 0, stream>>>(
      hb, W1T, b1, T1, EMBED, EMBED, EMBED, FFDIM, 1,
      0, 0, 0, 0, 0, 0, 1.0f, nullptr, nullptr, nullptr, nullptr);

  // FF2 split-K: K=4096 -> 2x2048; z = 2  (256 blocks); bias folded into LN2
  // lda = ldb = 4096 (T1 / W2T row stride), K = 2048 per half
  gemmx_kernel<2><<<dim3(EMBED / BNX, MTOK / BMX, 2), 512, 0, stream>>>(
      T1, W2T, nullptr, ff0, 2048, FFDIM, FFDIM, EMBED, 1,
      0, 0, 0,
      2048, 2048, sOk_ff,
      1.0f, nullptr, nullptr, nullptr, nullptr);

  // out = LN(ff0 + ff1 + b2 + h)
  ln_kernel<<<MTOK, 256, 0, stream>>>(ff0, ff1, h, b2, g2, be2, out, nullptr);
}

// Round 8
// 410.111 us; speedup vs baseline: 1.0643x; 1.0643x over previous
//
#include <hip/hip_runtime.h>
#include <hip/hip_bf16.h>
#include <cmath>
#include <cstdint>

typedef __bf16 bf16;
typedef __bf16 bf16x8 __attribute__((ext_vector_type(8)));
typedef __bf16 bf16x4 __attribute__((ext_vector_type(4)));
typedef float  f32x4  __attribute__((ext_vector_type(4)));

#define EMBED 1024
#define FFDIM 4096
#define BATCH 4
#define SEQ   2048
#define MTOK  (BATCH*SEQ)

// ---------------- workspace layout ----------------
static constexpr size_t OFF_XPE_F32 = 0;              // 32MB f32 (live until LN1)
static constexpr size_t OFF_XPE_B   = 32ull << 20;    // 16MB bf16; reused as h_bf16
static constexpr size_t OFF_Q       = 48ull << 20;    // 16MB bf16; Q..K reused as P (32MB); then FF2 part1
static constexpr size_t OFF_K       = 64ull << 20;    // 16MB bf16
static constexpr size_t OFF_VT      = 80ull << 20;    // 16MB bf16 [4][1024][2048]
static constexpr size_t OFF_E       = 96ull << 20;    // 64MB f32 E; then PV part1 (32MB); then T1 bf16
static constexpr size_t OFF_ATTN    = 160ull << 20;   // 32MB f32: PV part0; then FF2 part0
static constexpr size_t OFF_H       = 192ull << 20;   // 32MB f32 h
static constexpr size_t OFF_WQKVT   = 224ull << 20;   // 6MB bf16 [3072][1024]
static constexpr size_t OFF_W1T     = 230ull << 20;   // 8MB
static constexpr size_t OFF_W2T     = 238ull << 20;   // 8MB

// ---------------- wait/barrier primitives ----------------
#define VMCNT4 { asm volatile("s_waitcnt vmcnt(4)" ::: "memory"); __builtin_amdgcn_sched_barrier(0); }
#define VMCNT0 { asm volatile("s_waitcnt vmcnt(0)" ::: "memory"); __builtin_amdgcn_sched_barrier(0); }
#define PH_PRE  { __builtin_amdgcn_sched_barrier(0); __builtin_amdgcn_s_barrier(); \
                  asm volatile("s_waitcnt lgkmcnt(0)" ::: "memory"); __builtin_amdgcn_sched_barrier(0); }
#define PH_POST { __builtin_amdgcn_sched_barrier(0); __builtin_amdgcn_s_barrier(); \
                  __builtin_amdgcn_sched_barrier(0); }

__device__ __forceinline__ void gload_lds16(const void* g, void* l) {
  __builtin_amdgcn_global_load_lds((const __attribute__((address_space(1))) void*)g,
                                   (__attribute__((address_space(3))) void*)l, 16, 0, 0);
}

// ---------------- PE add ----------------
__global__ __launch_bounds__(256) void pe_add_kernel(const float* __restrict__ x,
                                                     float* __restrict__ xf,
                                                     bf16* __restrict__ xb) {
  int idx  = blockIdx.x * 256 + threadIdx.x;
  int pair = idx & 511;
  int s    = idx >> 9;
  float div = __expf((float)(2 * pair) * (-9.210340371976184f / (float)EMBED));
  float ang = (float)s * div;
  float sv = sinf(ang), cv = cosf(ang);
#pragma unroll
  for (int b = 0; b < BATCH; ++b) {
    size_t base = ((size_t)(b * SEQ + s)) * EMBED + (size_t)pair * 2;
    float v0 = x[base] + sv;
    float v1 = x[base + 1] + cv;
    xf[base] = v0; xf[base + 1] = v1;
    xb[base] = (bf16)v0; xb[base + 1] = (bf16)v1;
  }
}

// ---------------- weight transpose fp32[K][N] -> bf16[N][K] ----------------
__global__ __launch_bounds__(256) void transpose_kernel(const float* __restrict__ W,
                                                        bf16* __restrict__ Wt,
                                                        int K, int N) {
  __shared__ float tile[32][33];
  int nb = blockIdx.x * 32, kb = blockIdx.y * 32;
  int tx = threadIdx.x, ty = threadIdx.y;   // 32x8
#pragma unroll
  for (int i = 0; i < 32; i += 8)
    tile[ty + i][tx] = W[(size_t)(kb + ty + i) * N + nb + tx];
  __syncthreads();
#pragma unroll
  for (int i = 0; i < 32; i += 8)
    Wt[(size_t)(nb + ty + i) * K + kb + tx] = (bf16)tile[tx][ty + i];
}

// ---------------- gemm8: 256x256 tile, 8 waves (2Mx4N), 8-phase counted-vmcnt ----------------
// LDS 128KB: A[2buf][2qr][2wm][64][64], B[2buf][2qc][4wn][32][64], both XOR-swizzled.
// Per iter: 2 K-tiles, 8 phases {ds-read subtile | stage 1 half-tile | bar | lgkm0 |
// 16 MFMA (setprio) | bar}; vmcnt(4) only at phases 4 & 8.
// EPI 2: f32 *scale (+split-K)   EPI 3: bf16 +bias relu   EPI 6: fused QKV
#define BMX 256
#define BNX 256
#define BKX 64

#define MM16(QR, QC, FB) { \
  __builtin_amdgcn_s_setprio(1); \
  _Pragma("unroll") for (int kk = 0; kk < 2; ++kk) \
  _Pragma("unroll") for (int i2 = 0; i2 < 4; ++i2) \
  _Pragma("unroll") for (int j2 = 0; j2 < 2; ++j2) \
    acc[(QR)*4 + i2][(QC)*2 + j2] = __builtin_amdgcn_mfma_f32_16x16x32_bf16( \
        fa[kk][i2], FB[kk][j2], acc[(QR)*4 + i2][(QC)*2 + j2], 0, 0, 0); \
  __builtin_amdgcn_s_setprio(0); }

template <int EPI>
__global__ __launch_bounds__(512, 2) void gemm8_kernel(
    const bf16* __restrict__ A, const bf16* __restrict__ B,
    const float* __restrict__ bias, void* __restrict__ out,
    int K, int lda, int ldb, int ldo, int NB,
    long long sAz, long long sBz, long long sOz,
    long long sAk, long long sBk, long long sOk,
    float scale,
    const float* bias2, const float* bias3, void* out2, void* out3) {
  __shared__ __align__(16) char ldsA[2 * 32768];
  __shared__ __align__(16) char ldsB[2 * 32768];

  // T1: bijective XCD-chunked swizzle + grouped raster (G=8)
  const int gx = gridDim.x, gy = gridDim.y;
  int id = blockIdx.x + gx * (blockIdx.y + gy * blockIdx.z);
  const int nwg = gx * gy * gridDim.z;
  const int qd = nwg >> 3, rm = nwg & 7;
  const int xcd = id & 7, pos = id >> 3;
  const int lid = (xcd < rm ? xcd * (qd + 1) : rm * (qd + 1) + (xcd - rm) * qd) + pos;
  const int per = gx * gy;
  const int tz = lid / per;
  const int s2 = lid - tz * per;
  const int G = 8;
  const int ngrp = G * gy;
  const int grp = s2 / ngrp;
  const int within = s2 - grp * ngrp;
  const int gwf = gx - grp * G;
  const int gw = gwf < G ? gwf : G;
  const int tx = grp * G + within % gw;
  const int ty = within / gw;

  const int zb = tz % NB;
  const int kh = tz / NB;
  A += (long long)zb * sAz + (long long)kh * sAk;
  B += (long long)zb * sBz + (long long)kh * sBk;

  const int tid  = threadIdx.x;
  const int wave = tid >> 6;
  const int lane = tid & 63;
  const int wm = wave >> 2, wn = wave & 3;   // 2M x 4N
  const int rowBase = ty * BMX;
  const int colBase = tx * BNX;
  const int lr = lane & 15;
  const int g  = lane >> 4;
  const int lx = lr & 7;

  // staging bases: thread t -> rr = t>>3, slot (t&7)^(rr&7) (src pre-swizzled, rule 21)
  const int rr = tid >> 3;
  const int slot = (tid & 7) ^ (rr & 7);
  // A issue h of half qr: global row = rowBase + rr + h*128 + qr*64
  const bf16* Abase = A + (long long)(rowBase + rr) * lda + slot * 8;
  // B issue h of half qc: global col = colBase + (rr&31) + (h*2 + (rr>>5))*64 + qc*32
  const bf16* Bb0 = B + (long long)(colBase + (rr & 31) + ((rr >> 5)) * 64) * ldb + slot * 8;
  const bf16* Bb1 = B + (long long)(colBase + (rr & 31) + (2 + (rr >> 5)) * 64) * ldb + slot * 8;

  auto stA = [&](int T, int bufOff, int qr) {
    char* dst = ldsA + bufOff + qr * 16384 + wave * 1024;
    const bf16* s = Abase + (long long)(qr * 64) * lda + (long long)T * BKX;
    gload_lds16(s, dst);
    gload_lds16(s + (long long)128 * lda, dst + 8192);
  };
  auto stB = [&](int T, int bufOff, int qc) {
    char* dst = ldsB + bufOff + qc * 16384 + wave * 1024;
    const long long off = (long long)(qc * 32) * ldb + (long long)T * BKX;
    gload_lds16(Bb0 + off, dst);
    gload_lds16(Bb1 + off, dst + 8192);
  };

  bf16x8 fa[2][4], fbq0[2][2], fbq1[2][2];
  auto rdFA = [&](int bufOff, int qr) {
    const char* base = ldsA + bufOff + qr * 16384 + wm * 8192;
#pragma unroll
    for (int kk = 0; kk < 2; ++kk) {
      const int sw = ((kk * 4 + g) ^ lx) << 4;
#pragma unroll
      for (int i2 = 0; i2 < 4; ++i2)
        fa[kk][i2] = *(const bf16x8*)(base + (i2 * 16 + lr) * 128 + sw);
    }
  };
  auto rdFB = [&](int bufOff, int qc, bf16x8 fb[2][2]) {
    const char* base = ldsB + bufOff + qc * 16384 + wn * 4096;
#pragma unroll
    for (int kk = 0; kk < 2; ++kk) {
      const int sw = ((kk * 4 + g) ^ lx) << 4;
#pragma unroll
      for (int j2 = 0; j2 < 2; ++j2)
        fb[kk][j2] = *(const bf16x8*)(base + (j2 * 16 + lr) * 128 + sw);
    }
  };

  const f32x4 zero4 = {0.f, 0.f, 0.f, 0.f};
  f32x4 acc[8][4];
#pragma unroll
  for (int i = 0; i < 8; ++i)
#pragma unroll
    for (int j = 0; j < 4; ++j) acc[i][j] = zero4;

  const int nK = K / BKX;   // even (>= 16) for all launches here

  // prologue: tile0 (4 halves) + tile1 A-qr0, B-qc0; wait tile0 (leave 4 in flight)
  stA(0, 0, 0); stB(0, 0, 0); stA(0, 0, 1); stB(0, 0, 1);
  stA(1, 32768, 0); stB(1, 32768, 0);
  VMCNT4;
  __builtin_amdgcn_s_barrier(); __builtin_amdgcn_sched_barrier(0);

  // 8-phase iteration: tiles T0 (buf0) and T0+1 (buf1)
  // stage schedule: P1 hA1(T0+1) P2 hB1(T0+1) P3 hA0(T0+2) P4 hB0(T0+2)
  //                 P5 hA1(T0+2) P6 hB1(T0+2) P7 hA0(T0+3) P8 hB0(T0+3)
#define STEP(STG) { \
    rdFA(0, 0); rdFB(0, 0, fbq0); stA(T0 + 1, 32768, 1);            /* P1 */ \
    PH_PRE; MM16(0, 0, fbq0); PH_POST; \
    rdFB(0, 1, fbq1); stB(T0 + 1, 32768, 1);                        /* P2 */ \
    PH_PRE; MM16(0, 1, fbq1); PH_POST; \
    rdFA(0, 1); if (STG) stA(T0 + 2, 0, 0);                         /* P3 */ \
    PH_PRE; MM16(1, 0, fbq0); PH_POST; \
    if (STG) stB(T0 + 2, 0, 0);                                     /* P4 */ \
    PH_PRE; MM16(1, 1, fbq1); \
    if (STG) { VMCNT4 } else { VMCNT0 } \
    PH_POST; \
    rdFA(32768, 0); rdFB(32768, 0, fbq0); if (STG) stA(T0 + 2, 0, 1); /* P5 */ \
    PH_PRE; MM16(0, 0, fbq0); PH_POST; \
    rdFB(32768, 1, fbq1); if (STG) stB(T0 + 2, 0, 1);               /* P6 */ \
    PH_PRE; MM16(0, 1, fbq1); PH_POST; \
    rdFA(32768, 1); if (STG) stA(T0 + 3, 32768, 0);                 /* P7 */ \
    PH_PRE; MM16(1, 0, fbq0); PH_POST; \
    if (STG) stB(T0 + 3, 32768, 0);                                 /* P8 */ \
    PH_PRE; MM16(1, 1, fbq1); \
    if (STG) { VMCNT4 } \
    PH_POST; \
  }

  int T0 = 0;
  for (; T0 + 2 < nK; T0 += 2) STEP(1);
  STEP(0);
#undef STEP

  // epilogue: C/D col = lane&15, row = (lane>>4)*4 + reg [m89]; quadrant remap:
  // row = rowBase + wm*128 + (i>>2)*64 + (i&3)*16 + g*4 ; col = colBase + wn*64 + (j>>1)*32 + (j&1)*16 + lr
#pragma unroll
  for (int j = 0; j < 4; ++j) {
    const int col = colBase + wn * 64 + (j >> 1) * 32 + (j & 1) * 16 + lr;
#pragma unroll
    for (int i = 0; i < 8; ++i) {
      const int row0 = rowBase + wm * 128 + (i >> 2) * 64 + (i & 3) * 16 + g * 4;
      if constexpr (EPI == 6) {
        const int cb = col >> 10;        // uniform per block (colBase mult of 256)
        const int c  = col & 1023;
        const float bv = (cb == 0 ? bias : (cb == 1 ? bias2 : bias3))[c];
        if (cb == 2) {
          const int b_ = row0 >> 11;
          const int s_ = row0 & (SEQ - 1);
          bf16x4 pv;
#pragma unroll
          for (int rr2 = 0; rr2 < 4; ++rr2) pv[rr2] = (bf16)(acc[i][j][rr2] + bv);
          *(bf16x4*)((bf16*)out3 + ((size_t)b_ * EMBED + c) * SEQ + s_) = pv;
        } else {
          bf16* dst = (cb == 0 ? (bf16*)out : (bf16*)out2);
#pragma unroll
          for (int rr2 = 0; rr2 < 4; ++rr2)
            dst[(size_t)(row0 + rr2) * EMBED + c] = (bf16)(acc[i][j][rr2] + bv);
        }
      } else if constexpr (EPI == 2) {
        float* dst = (float*)out + (long long)zb * sOz + (long long)kh * sOk;
#pragma unroll
        for (int rr2 = 0; rr2 < 4; ++rr2)
          dst[(long long)(row0 + rr2) * ldo + col] = acc[i][j][rr2] * scale;
      } else if constexpr (EPI == 3) {
        const float bv = bias[col];
#pragma unroll
        for (int rr2 = 0; rr2 < 4; ++rr2) {
          float t = acc[i][j][rr2] + bv;
          ((bf16*)out)[(size_t)(row0 + rr2) * ldo + col] = (bf16)(t > 0.f ? t : 0.f);
        }
      }
    }
  }
}

// ---------------- row softmax: E f32 [rows][SEQ] -> P bf16 ----------------
__global__ __launch_bounds__(256) void softmax_kernel(const float* __restrict__ E,
                                                      bf16* __restrict__ P) {
  const size_t row = blockIdx.x;
  const float* e = E + row * SEQ;
  const int t = threadIdx.x;
  float4 a = ((const float4*)e)[2 * t];
  float4 b = ((const float4*)e)[2 * t + 1];
  float m = fmaxf(fmaxf(fmaxf(a.x, a.y), fmaxf(a.z, a.w)),
                  fmaxf(fmaxf(b.x, b.y), fmaxf(b.z, b.w)));
#pragma unroll
  for (int o = 32; o; o >>= 1) m = fmaxf(m, __shfl_xor(m, o));
  __shared__ float red[8];
  const int w = t >> 6;
  if ((t & 63) == 0) red[w] = m;
  __syncthreads();
  m = fmaxf(fmaxf(red[0], red[1]), fmaxf(red[2], red[3]));
  float ex[8];
  ex[0] = __expf(a.x - m); ex[1] = __expf(a.y - m);
  ex[2] = __expf(a.z - m); ex[3] = __expf(a.w - m);
  ex[4] = __expf(b.x - m); ex[5] = __expf(b.y - m);
  ex[6] = __expf(b.z - m); ex[7] = __expf(b.w - m);
  float s = ex[0] + ex[1] + ex[2] + ex[3] + ex[4] + ex[5] + ex[6] + ex[7];
#pragma unroll
  for (int o = 32; o; o >>= 1) s += __shfl_xor(s, o);
  if ((t & 63) == 0) red[4 + w] = s;
  __syncthreads();
  s = red[4] + red[5] + red[6] + red[7];
  const float inv = 1.0f / s;
  bf16x8 pv;
#pragma unroll
  for (int q = 0; q < 8; ++q) pv[q] = (bf16)(ex[q] * inv);
  *(bf16x8*)(P + row * SEQ + (size_t)t * 8) = pv;
}

// ---------------- LayerNorm: out = LN(X [+X2] [+cb] + R) * g + b ----------------
__global__ __launch_bounds__(256) void ln_kernel(const float* __restrict__ X,
                                                 const float* __restrict__ X2,
                                                 const float* __restrict__ R,
                                                 const float* __restrict__ cb,
                                                 const float* __restrict__ gm,
                                                 const float* __restrict__ bt,
                                                 float* __restrict__ of,
                                                 bf16* __restrict__ ob) {
  const size_t row = blockIdx.x;
  const int t = threadIdx.x;
  float4 xv = ((const float4*)(X + row * EMBED))[t];
  float4 rv = ((const float4*)(R + row * EMBED))[t];
  float4 v;
  v.x = xv.x + rv.x; v.y = xv.y + rv.y; v.z = xv.z + rv.z; v.w = xv.w + rv.w;
  if (X2) {
    float4 x2 = ((const float4*)(X2 + row * EMBED))[t];
    v.x += x2.x; v.y += x2.y; v.z += x2.z; v.w += x2.w;
  }
  if (cb) {
    float4 c4 = ((const float4*)cb)[t];
    v.x += c4.x; v.y += c4.y; v.z += c4.z; v.w += c4.w;
  }
  float s  = v.x + v.y + v.z + v.w;
  float ss = v.x * v.x + v.y * v.y + v.z * v.z + v.w * v.w;
#pragma unroll
  for (int o = 32; o; o >>= 1) { s += __shfl_xor(s, o); ss += __shfl_xor(ss, o); }
  __shared__ float red[8];
  const int w = t >> 6;
  if ((t & 63) == 0) { red[w] = s; red[4 + w] = ss; }
  __syncthreads();
  s  = red[0] + red[1] + red[2] + red[3];
  ss = red[4] + red[5] + red[6] + red[7];
  const float mu  = s * (1.0f / EMBED);
  const float inv = rsqrtf(ss * (1.0f / EMBED) - mu * mu + 1e-5f);
  float4 gv = ((const float4*)gm)[t];
  float4 bv = ((const float4*)bt)[t];
  float4 o4;
  o4.x = (v.x - mu) * inv * gv.x + bv.x;
  o4.y = (v.y - mu) * inv * gv.y + bv.y;
  o4.z = (v.z - mu) * inv * gv.z + bv.z;
  o4.w = (v.w - mu) * inv * gv.w + bv.w;
  if (of) ((float4*)(of + row * EMBED))[t] = o4;
  if (ob) {
    bf16x4 p;
    p[0] = (bf16)o4.x; p[1] = (bf16)o4.y; p[2] = (bf16)o4.z; p[3] = (bf16)o4.w;
    *(bf16x4*)(ob + row * EMBED + (size_t)t * 4) = p;
  }
}

// ---------------- launch ----------------
extern "C" void kernel_launch(void* const* d_in, const int* in_sizes, int n_in,
                              void* d_out, int out_size, void* d_ws, size_t ws_size,
                              hipStream_t stream) {
  const float* x   = (const float*)d_in[0];
  const float* Wq  = (const float*)d_in[1];
  const float* bq  = (const float*)d_in[2];
  const float* Wk  = (const float*)d_in[3];
  const float* bk  = (const float*)d_in[4];
  const float* Wv  = (const float*)d_in[5];
  const float* bv  = (const float*)d_in[6];
  const float* W1  = (const float*)d_in[7];
  const float* b1  = (const float*)d_in[8];
  const float* W2  = (const float*)d_in[9];
  const float* b2  = (const float*)d_in[10];
  const float* g1  = (const float*)d_in[11];
  const float* be1 = (const float*)d_in[12];
  const float* g2  = (const float*)d_in[13];
  const float* be2 = (const float*)d_in[14];
  float* out = (float*)d_out;
  char* ws = (char*)d_ws;

  float* xpe  = (float*)(ws + OFF_XPE_F32);
  bf16*  xpeb = (bf16*)(ws + OFF_XPE_B);
  bf16*  Qb   = (bf16*)(ws + OFF_Q);
  bf16*  Kb   = (bf16*)(ws + OFF_K);
  bf16*  VT   = (bf16*)(ws + OFF_VT);
  float* E    = (float*)(ws + OFF_E);
  bf16*  P    = (bf16*)(ws + OFF_Q);      // reuse Q+K region after QK^T
  float* pv0  = (float*)(ws + OFF_ATTN);  // PV part 0
  float* pv1  = (float*)(ws + OFF_E);     // PV part 1 (E dead after softmax)
  bf16*  T1   = (bf16*)(ws + OFF_E);      // FF1 out (pv1 dead after LN1)
  float* ff0  = (float*)(ws + OFF_ATTN);  // FF2 part 0
  float* ff1  = (float*)(ws + OFF_Q);     // FF2 part 1 (P dead after PV)
  float* h    = (float*)(ws + OFF_H);
  bf16*  hb   = (bf16*)(ws + OFF_XPE_B);
  bf16*  WqkvT = (bf16*)(ws + OFF_WQKVT);
  bf16*  W1T  = (bf16*)(ws + OFF_W1T);
  bf16*  W2T  = (bf16*)(ws + OFF_W2T);

  const long long sOk_pv = (long long)(OFF_E / 4) - (long long)(OFF_ATTN / 4);
  const long long sOk_ff = (long long)(OFF_Q / 4) - (long long)(OFF_ATTN / 4);

  const dim3 tb(32, 8);
  transpose_kernel<<<dim3(EMBED / 32, EMBED / 32), tb, 0, stream>>>(Wq, WqkvT, EMBED, EMBED);
  transpose_kernel<<<dim3(EMBED / 32, EMBED / 32), tb, 0, stream>>>(Wk, WqkvT + (size_t)EMBED * EMBED, EMBED, EMBED);
  transpose_kernel<<<dim3(EMBED / 32, EMBED / 32), tb, 0, stream>>>(Wv, WqkvT + 2ull * EMBED * EMBED, EMBED, EMBED);
  transpose_kernel<<<dim3(FFDIM / 32, EMBED / 32), tb, 0, stream>>>(W1, W1T, EMBED, FFDIM);
  transpose_kernel<<<dim3(EMBED / 32, FFDIM / 32), tb, 0, stream>>>(W2, W2T, FFDIM, EMBED);

  pe_add_kernel<<<(SEQ * 512) / 256, 256, 0, stream>>>(x, xpe, xpeb);

  // fused QKV (384 blocks)
  gemm8_kernel<6><<<dim3(3072 / BNX, MTOK / BMX, 1), 512, 0, stream>>>(
      xpeb, WqkvT, bq, Qb, EMBED, EMBED, EMBED, EMBED, 1,
      0, 0, 0, 0, 0, 0, 1.0f, bk, bv, Kb, VT);

  // QK^T: E = Q @ K^T / 32  (256 blocks)
  gemm8_kernel<2><<<dim3(SEQ / BNX, SEQ / BMX, BATCH), 512, 0, stream>>>(
      Qb, Kb, nullptr, E, EMBED, EMBED, EMBED, SEQ, BATCH,
      (long long)SEQ * EMBED, (long long)SEQ * EMBED, (long long)SEQ * SEQ,
      0, 0, 0, 0.03125f, nullptr, nullptr, nullptr, nullptr);

  softmax_kernel<<<BATCH * SEQ, 256, 0, stream>>>(E, P);

  // PV split-K: K=2048 -> 2x1024 (256 blocks)
  gemm8_kernel<2><<<dim3(EMBED / BNX, SEQ / BMX, BATCH * 2), 512, 0, stream>>>(
      P, VT, nullptr, pv0, 1024, SEQ, SEQ, EMBED, BATCH,
      (long long)SEQ * SEQ, (long long)EMBED * SEQ, (long long)SEQ * EMBED,
      1024, 1024, sOk_pv,
      1.0f, nullptr, nullptr, nullptr, nullptr);

  // h = LN(pv0 + pv1 + xpe)
  ln_kernel<<<MTOK, 256, 0, stream>>>(pv0, pv1, xpe, nullptr, g1, be1, h, hb);

  // FF1: relu(h @ W1 + b1)  (512 blocks)
  gemm8_kernel<3><<<dim3(FFDIM / BNX, MTOK / BMX, 1), 512, 0, stream>>>(
      hb, W1T, b1, T1, EMBED, EMBED, EMBED, FFDIM, 1,
      0, 0, 0, 0, 0, 0, 1.0f, nullptr, nullptr, nullptr, nullptr);

  // FF2 split-K: K=4096 -> 2x2048 (256 blocks); bias folded into LN2
  gemm8_kernel<2><<<dim3(EMBED / BNX, MTOK / BMX, 2), 512, 0, stream>>>(
      T1, W2T, nullptr, ff0, 2048, FFDIM, FFDIM, EMBED, 1,
      0, 0, 0,
      2048, 2048, sOk_ff,
      1.0f, nullptr, nullptr, nullptr, nullptr);

  // out = LN(ff0 + ff1 + b2 + h)
  ln_kernel<<<MTOK, 256, 0, stream>>>(ff0, ff1, h, b2, g2, be2, out, nullptr);
}

// Round 9
// 396.111 us; speedup vs baseline: 1.1020x; 1.0353x over previous
//
#include <hip/hip_runtime.h>
#include <hip/hip_bf16.h>
#include <cmath>
#include <cstdint>

typedef __bf16 bf16;
typedef __bf16 bf16x8 __attribute__((ext_vector_type(8)));
typedef __bf16 bf16x4 __attribute__((ext_vector_type(4)));
typedef float  f32x4  __attribute__((ext_vector_type(4)));

#define EMBED 1024
#define FFDIM 4096
#define BATCH 4
#define SEQ   2048
#define MTOK  (BATCH*SEQ)

// ---------------- workspace layout ----------------
static constexpr size_t OFF_XPE_F32 = 0;              // 32MB f32 (live until LN1)
static constexpr size_t OFF_XPE_B   = 32ull << 20;    // 16MB bf16; reused as h_bf16
static constexpr size_t OFF_Q       = 48ull << 20;    // 16MB bf16; Q..K reused as P (32MB); then FF2 part1
static constexpr size_t OFF_K       = 64ull << 20;    // 16MB bf16
static constexpr size_t OFF_VT      = 80ull << 20;    // 16MB bf16 [4][1024][2048]
static constexpr size_t OFF_E       = 96ull << 20;    // 64MB f32 E; then PV part1 (32MB); then T1 bf16
static constexpr size_t OFF_ATTN    = 160ull << 20;   // 32MB f32: PV part0; then FF2 part0
static constexpr size_t OFF_H       = 192ull << 20;   // 32MB f32 h
static constexpr size_t OFF_WQKVT   = 224ull << 20;   // 6MB bf16 [3072][1024]
static constexpr size_t OFF_W1T     = 230ull << 20;   // 8MB
static constexpr size_t OFF_W2T     = 238ull << 20;   // 8MB

// ---------------- wait/barrier primitives ----------------
#define VMCNT4 { asm volatile("s_waitcnt vmcnt(4)" ::: "memory"); __builtin_amdgcn_sched_barrier(0); }
#define VMCNT0 { asm volatile("s_waitcnt vmcnt(0)" ::: "memory"); __builtin_amdgcn_sched_barrier(0); }
// pre-MFMA fence: barrier then per-wave lgkm drain (reads were issued before barrier)
#define PH_BAR  { __builtin_amdgcn_sched_barrier(0); __builtin_amdgcn_s_barrier(); \
                  asm volatile("s_waitcnt lgkmcnt(0)" ::: "memory"); __builtin_amdgcn_sched_barrier(0); }
// order pin after an MFMA cluster (no barrier — allows wave-stagger overlap)
#define PH_END  { __builtin_amdgcn_sched_barrier(0); }
// plain block barrier (after vmcnt drains, before reads of newly staged halves)
#define BARONLY { __builtin_amdgcn_sched_barrier(0); __builtin_amdgcn_s_barrier(); \
                  __builtin_amdgcn_sched_barrier(0); }

__device__ __forceinline__ void gload_lds16(const void* g, void* l) {
  __builtin_amdgcn_global_load_lds((const __attribute__((address_space(1))) void*)g,
                                   (__attribute__((address_space(3))) void*)l, 16, 0, 0);
}

// ---------------- PE add ----------------
__global__ __launch_bounds__(256) void pe_add_kernel(const float* __restrict__ x,
                                                     float* __restrict__ xf,
                                                     bf16* __restrict__ xb) {
  int idx  = blockIdx.x * 256 + threadIdx.x;
  int pair = idx & 511;
  int s    = idx >> 9;
  float div = __expf((float)(2 * pair) * (-9.210340371976184f / (float)EMBED));
  float ang = (float)s * div;
  float sv = sinf(ang), cv = cosf(ang);
#pragma unroll
  for (int b = 0; b < BATCH; ++b) {
    size_t base = ((size_t)(b * SEQ + s)) * EMBED + (size_t)pair * 2;
    float v0 = x[base] + sv;
    float v1 = x[base + 1] + cv;
    xf[base] = v0; xf[base + 1] = v1;
    xb[base] = (bf16)v0; xb[base + 1] = (bf16)v1;
  }
}

// ---------------- weight transpose fp32[K][N] -> bf16[N][K] ----------------
__global__ __launch_bounds__(256) void transpose_kernel(const float* __restrict__ W,
                                                        bf16* __restrict__ Wt,
                                                        int K, int N) {
  __shared__ float tile[32][33];
  int nb = blockIdx.x * 32, kb = blockIdx.y * 32;
  int tx = threadIdx.x, ty = threadIdx.y;   // 32x8
#pragma unroll
  for (int i = 0; i < 32; i += 8)
    tile[ty + i][tx] = W[(size_t)(kb + ty + i) * N + nb + tx];
  __syncthreads();
#pragma unroll
  for (int i = 0; i < 32; i += 8)
    Wt[(size_t)(nb + ty + i) * K + kb + tx] = (bf16)tile[tx][ty + i];
}

// ---------------- gemm8: 256x256 tile, 8 waves (2Mx4N), 8-phase counted-vmcnt ----------------
// LDS 128KB: A[2buf][2qr][2wm][64][64], B[2buf][2qc][4wn][32][64], both XOR-swizzled.
// Round 9: single barrier per phase (pre-MFMA), none for P4/P8 (reg-fed MFMA);
// vmcnt(4)+barrier only at P4/P8 ends. 8 barriers / 2 K-tiles.
// EPI 2: f32 *scale (+split-K)   EPI 3: bf16 +bias relu   EPI 6: fused QKV
#define BMX 256
#define BNX 256
#define BKX 64

#define MM16(QR, QC, FB) { \
  __builtin_amdgcn_s_setprio(1); \
  _Pragma("unroll") for (int kk = 0; kk < 2; ++kk) \
  _Pragma("unroll") for (int i2 = 0; i2 < 4; ++i2) \
  _Pragma("unroll") for (int j2 = 0; j2 < 2; ++j2) \
    acc[(QR)*4 + i2][(QC)*2 + j2] = __builtin_amdgcn_mfma_f32_16x16x32_bf16( \
        fa[kk][i2], FB[kk][j2], acc[(QR)*4 + i2][(QC)*2 + j2], 0, 0, 0); \
  __builtin_amdgcn_s_setprio(0); }

template <int EPI>
__global__ __launch_bounds__(512, 2) void gemm8_kernel(
    const bf16* __restrict__ A, const bf16* __restrict__ B,
    const float* __restrict__ bias, void* __restrict__ out,
    int K, int lda, int ldb, int ldo, int NB,
    long long sAz, long long sBz, long long sOz,
    long long sAk, long long sBk, long long sOk,
    float scale,
    const float* bias2, const float* bias3, void* out2, void* out3) {
  __shared__ __align__(16) char ldsA[2 * 32768];
  __shared__ __align__(16) char ldsB[2 * 32768];

  // T1: bijective XCD-chunked swizzle + grouped raster (G=8)
  const int gx = gridDim.x, gy = gridDim.y;
  int id = blockIdx.x + gx * (blockIdx.y + gy * blockIdx.z);
  const int nwg = gx * gy * gridDim.z;
  const int qd = nwg >> 3, rm = nwg & 7;
  const int xcd = id & 7, pos = id >> 3;
  const int lid = (xcd < rm ? xcd * (qd + 1) : rm * (qd + 1) + (xcd - rm) * qd) + pos;
  const int per = gx * gy;
  const int tz = lid / per;
  const int s2 = lid - tz * per;
  const int G = 8;
  const int ngrp = G * gy;
  const int grp = s2 / ngrp;
  const int within = s2 - grp * ngrp;
  const int gwf = gx - grp * G;
  const int gw = gwf < G ? gwf : G;
  const int tx = grp * G + within % gw;
  const int ty = within / gw;

  const int zb = tz % NB;
  const int kh = tz / NB;
  A += (long long)zb * sAz + (long long)kh * sAk;
  B += (long long)zb * sBz + (long long)kh * sBk;

  const int tid  = threadIdx.x;
  const int wave = tid >> 6;
  const int lane = tid & 63;
  const int wm = wave >> 2, wn = wave & 3;   // 2M x 4N
  const int rowBase = ty * BMX;
  const int colBase = tx * BNX;
  const int lr = lane & 15;
  const int g  = lane >> 4;
  const int lx = lr & 7;

  // staging bases: thread t -> rr = t>>3, slot (t&7)^(rr&7) (src pre-swizzled, rule 21)
  const int rr = tid >> 3;
  const int slot = (tid & 7) ^ (rr & 7);
  const bf16* Abase = A + (long long)(rowBase + rr) * lda + slot * 8;
  const bf16* Bb0 = B + (long long)(colBase + (rr & 31) + ((rr >> 5)) * 64) * ldb + slot * 8;
  const bf16* Bb1 = B + (long long)(colBase + (rr & 31) + (2 + (rr >> 5)) * 64) * ldb + slot * 8;

  auto stA = [&](int T, int bufOff, int qr) {
    char* dst = ldsA + bufOff + qr * 16384 + wave * 1024;
    const bf16* s = Abase + (long long)(qr * 64) * lda + (long long)T * BKX;
    gload_lds16(s, dst);
    gload_lds16(s + (long long)128 * lda, dst + 8192);
  };
  auto stB = [&](int T, int bufOff, int qc) {
    char* dst = ldsB + bufOff + qc * 16384 + wave * 1024;
    const long long off = (long long)(qc * 32) * ldb + (long long)T * BKX;
    gload_lds16(Bb0 + off, dst);
    gload_lds16(Bb1 + off, dst + 8192);
  };

  bf16x8 fa[2][4], fbq0[2][2], fbq1[2][2];
  auto rdFA = [&](int bufOff, int qr) {
    const char* base = ldsA + bufOff + qr * 16384 + wm * 8192;
#pragma unroll
    for (int kk = 0; kk < 2; ++kk) {
      const int sw = ((kk * 4 + g) ^ lx) << 4;
#pragma unroll
      for (int i2 = 0; i2 < 4; ++i2)
        fa[kk][i2] = *(const bf16x8*)(base + (i2 * 16 + lr) * 128 + sw);
    }
  };
  auto rdFB = [&](int bufOff, int qc, bf16x8 fb[2][2]) {
    const char* base = ldsB + bufOff + qc * 16384 + wn * 4096;
#pragma unroll
    for (int kk = 0; kk < 2; ++kk) {
      const int sw = ((kk * 4 + g) ^ lx) << 4;
#pragma unroll
      for (int j2 = 0; j2 < 2; ++j2)
        fb[kk][j2] = *(const bf16x8*)(base + (j2 * 16 + lr) * 128 + sw);
    }
  };

  const f32x4 zero4 = {0.f, 0.f, 0.f, 0.f};
  f32x4 acc[8][4];
#pragma unroll
  for (int i = 0; i < 8; ++i)
#pragma unroll
    for (int j = 0; j < 4; ++j) acc[i][j] = zero4;

  const int nK = K / BKX;   // even (>= 16) for all launches here

  // prologue: tile0 (4 halves) + tile1 A-qr0, B-qc0; wait tile0 (leave 4 in flight)
  stA(0, 0, 0); stB(0, 0, 0); stA(0, 0, 1); stB(0, 0, 1);
  stA(1, 32768, 0); stB(1, 32768, 0);
  VMCNT4;
  __builtin_amdgcn_s_barrier(); __builtin_amdgcn_sched_barrier(0);

  // 8-phase iteration over tiles T0 (buf0) and T0+1 (buf1).
  // stage schedule (target last read >=2 phases earlier; skew bounded by barriers):
  //   P1 hA1(T0+1) P2 hB1(T0+1) P3 hA0(T0+2) P4 hB0(T0+2)
  //   P5 hA1(T0+2) P6 hB1(T0+2) P7 hA0(T0+3) P8 hB0(T0+3)
  // vmcnt(4)+barrier only at ends of P4/P8 (drains exactly the halves read next 4 phases).
#define STEP(STG) { \
    rdFA(0, 0); rdFB(0, 0, fbq0); stA(T0 + 1, 32768, 1);              /* P1 */ \
    PH_BAR; MM16(0, 0, fbq0); PH_END; \
    rdFB(0, 1, fbq1); stB(T0 + 1, 32768, 1);                          /* P2 */ \
    PH_BAR; MM16(0, 1, fbq1); PH_END; \
    rdFA(0, 1); if (STG) stA(T0 + 2, 0, 0);                           /* P3 */ \
    PH_BAR; MM16(1, 0, fbq0); PH_END; \
    if (STG) stB(T0 + 2, 0, 0);                                       /* P4 */ \
    MM16(1, 1, fbq1); \
    if (STG) { VMCNT4 } else { VMCNT0 } \
    BARONLY; \
    rdFA(32768, 0); rdFB(32768, 0, fbq0); if (STG) stA(T0 + 2, 0, 1); /* P5 */ \
    PH_BAR; MM16(0, 0, fbq0); PH_END; \
    rdFB(32768, 1, fbq1); if (STG) stB(T0 + 2, 0, 1);                 /* P6 */ \
    PH_BAR; MM16(0, 1, fbq1); PH_END; \
    rdFA(32768, 1); if (STG) stA(T0 + 3, 32768, 0);                   /* P7 */ \
    PH_BAR; MM16(1, 0, fbq0); PH_END; \
    if (STG) stB(T0 + 3, 32768, 0);                                   /* P8 */ \
    MM16(1, 1, fbq1); \
    if (STG) { VMCNT4 } \
    BARONLY; \
  }

  int T0 = 0;
  for (; T0 + 2 < nK; T0 += 2) STEP(1);
  STEP(0);
#undef STEP

  // epilogue: C/D col = lane&15, row = (lane>>4)*4 + reg [m89]; quadrant remap:
  // row = rowBase + wm*128 + (i>>2)*64 + (i&3)*16 + g*4 ; col = colBase + wn*64 + (j>>1)*32 + (j&1)*16 + lr
#pragma unroll
  for (int j = 0; j < 4; ++j) {
    const int col = colBase + wn * 64 + (j >> 1) * 32 + (j & 1) * 16 + lr;
#pragma unroll
    for (int i = 0; i < 8; ++i) {
      const int row0 = rowBase + wm * 128 + (i >> 2) * 64 + (i & 3) * 16 + g * 4;
      if constexpr (EPI == 6) {
        const int cb = col >> 10;        // uniform per block (colBase mult of 256)
        const int c  = col & 1023;
        const float bv = (cb == 0 ? bias : (cb == 1 ? bias2 : bias3))[c];
        if (cb == 2) {
          const int b_ = row0 >> 11;
          const int s_ = row0 & (SEQ - 1);
          bf16x4 pv;
#pragma unroll
          for (int rr2 = 0; rr2 < 4; ++rr2) pv[rr2] = (bf16)(acc[i][j][rr2] + bv);
          *(bf16x4*)((bf16*)out3 + ((size_t)b_ * EMBED + c) * SEQ + s_) = pv;
        } else {
          bf16* dst = (cb == 0 ? (bf16*)out : (bf16*)out2);
#pragma unroll
          for (int rr2 = 0; rr2 < 4; ++rr2)
            dst[(size_t)(row0 + rr2) * EMBED + c] = (bf16)(acc[i][j][rr2] + bv);
        }
      } else if constexpr (EPI == 2) {
        float* dst = (float*)out + (long long)zb * sOz + (long long)kh * sOk;
#pragma unroll
        for (int rr2 = 0; rr2 < 4; ++rr2)
          dst[(long long)(row0 + rr2) * ldo + col] = acc[i][j][rr2] * scale;
      } else if constexpr (EPI == 3) {
        const float bv = bias[col];
#pragma unroll
        for (int rr2 = 0; rr2 < 4; ++rr2) {
          float t = acc[i][j][rr2] + bv;
          ((bf16*)out)[(size_t)(row0 + rr2) * ldo + col] = (bf16)(t > 0.f ? t : 0.f);
        }
      }
    }
  }
}

// ---------------- row softmax: E f32 [rows][SEQ] -> P bf16 ----------------
__global__ __launch_bounds__(256) void softmax_kernel(const float* __restrict__ E,
                                                      bf16* __restrict__ P) {
  const size_t row = blockIdx.x;
  const float* e = E + row * SEQ;
  const int t = threadIdx.x;
  float4 a = ((const float4*)e)[2 * t];
  float4 b = ((const float4*)e)[2 * t + 1];
  float m = fmaxf(fmaxf(fmaxf(a.x, a.y), fmaxf(a.z, a.w)),
                  fmaxf(fmaxf(b.x, b.y), fmaxf(b.z, b.w)));
#pragma unroll
  for (int o = 32; o; o >>= 1) m = fmaxf(m, __shfl_xor(m, o));
  __shared__ float red[8];
  const int w = t >> 6;
  if ((t & 63) == 0) red[w] = m;
  __syncthreads();
  m = fmaxf(fmaxf(red[0], red[1]), fmaxf(red[2], red[3]));
  float ex[8];
  ex[0] = __expf(a.x - m); ex[1] = __expf(a.y - m);
  ex[2] = __expf(a.z - m); ex[3] = __expf(a.w - m);
  ex[4] = __expf(b.x - m); ex[5] = __expf(b.y - m);
  ex[6] = __expf(b.z - m); ex[7] = __expf(b.w - m);
  float s = ex[0] + ex[1] + ex[2] + ex[3] + ex[4] + ex[5] + ex[6] + ex[7];
#pragma unroll
  for (int o = 32; o; o >>= 1) s += __shfl_xor(s, o);
  if ((t & 63) == 0) red[4 + w] = s;
  __syncthreads();
  s = red[4] + red[5] + red[6] + red[7];
  const float inv = 1.0f / s;
  bf16x8 pv;
#pragma unroll
  for (int q = 0; q < 8; ++q) pv[q] = (bf16)(ex[q] * inv);
  *(bf16x8*)(P + row * SEQ + (size_t)t * 8) = pv;
}

// ---------------- LayerNorm: out = LN(X [+X2] [+cb] + R) * g + b ----------------
__global__ __launch_bounds__(256) void ln_kernel(const float* __restrict__ X,
                                                 const float* __restrict__ X2,
                                                 const float* __restrict__ R,
                                                 const float* __restrict__ cb,
                                                 const float* __restrict__ gm,
                                                 const float* __restrict__ bt,
                                                 float* __restrict__ of,
                                                 bf16* __restrict__ ob) {
  const size_t row = blockIdx.x;
  const int t = threadIdx.x;
  float4 xv = ((const float4*)(X + row * EMBED))[t];
  float4 rv = ((const float4*)(R + row * EMBED))[t];
  float4 v;
  v.x = xv.x + rv.x; v.y = xv.y + rv.y; v.z = xv.z + rv.z; v.w = xv.w + rv.w;
  if (X2) {
    float4 x2 = ((const float4*)(X2 + row * EMBED))[t];
    v.x += x2.x; v.y += x2.y; v.z += x2.z; v.w += x2.w;
  }
  if (cb) {
    float4 c4 = ((const float4*)cb)[t];
    v.x += c4.x; v.y += c4.y; v.z += c4.z; v.w += c4.w;
  }
  float s  = v.x + v.y + v.z + v.w;
  float ss = v.x * v.x + v.y * v.y + v.z * v.z + v.w * v.w;
#pragma unroll
  for (int o = 32; o; o >>= 1) { s += __shfl_xor(s, o); ss += __shfl_xor(ss, o); }
  __shared__ float red[8];
  const int w = t >> 6;
  if ((t & 63) == 0) { red[w] = s; red[4 + w] = ss; }
  __syncthreads();
  s  = red[0] + red[1] + red[2] + red[3];
  ss = red[4] + red[5] + red[6] + red[7];
  const float mu  = s * (1.0f / EMBED);
  const float inv = rsqrtf(ss * (1.0f / EMBED) - mu * mu + 1e-5f);
  float4 gv = ((const float4*)gm)[t];
  float4 bv = ((const float4*)bt)[t];
  float4 o4;
  o4.x = (v.x - mu) * inv * gv.x + bv.x;
  o4.y = (v.y - mu) * inv * gv.y + bv.y;
  o4.z = (v.z - mu) * inv * gv.z + bv.z;
  o4.w = (v.w - mu) * inv * gv.w + bv.w;
  if (of) ((float4*)(of + row * EMBED))[t] = o4;
  if (ob) {
    bf16x4 p;
    p[0] = (bf16)o4.x; p[1] = (bf16)o4.y; p[2] = (bf16)o4.z; p[3] = (bf16)o4.w;
    *(bf16x4*)(ob + row * EMBED + (size_t)t * 4) = p;
  }
}

// ---------------- launch ----------------
extern "C" void kernel_launch(void* const* d_in, const int* in_sizes, int n_in,
                              void* d_out, int out_size, void* d_ws, size_t ws_size,
                              hipStream_t stream) {
  const float* x   = (const float*)d_in[0];
  const float* Wq  = (const float*)d_in[1];
  const float* bq  = (const float*)d_in[2];
  const float* Wk  = (const float*)d_in[3];
  const float* bk  = (const float*)d_in[4];
  const float* Wv  = (const float*)d_in[5];
  const float* bv  = (const float*)d_in[6];
  const float* W1  = (const float*)d_in[7];
  const float* b1  = (const float*)d_in[8];
  const float* W2  = (const float*)d_in[9];
  const float* b2  = (const float*)d_in[10];
  const float* g1  = (const float*)d_in[11];
  const float* be1 = (const float*)d_in[12];
  const float* g2  = (const float*)d_in[13];
  const float* be2 = (const float*)d_in[14];
  float* out = (float*)d_out;
  char* ws = (char*)d_ws;

  float* xpe  = (float*)(ws + OFF_XPE_F32);
  bf16*  xpeb = (bf16*)(ws + OFF_XPE_B);
  bf16*  Qb   = (bf16*)(ws + OFF_Q);
  bf16*  Kb   = (bf16*)(ws + OFF_K);
  bf16*  VT   = (bf16*)(ws + OFF_VT);
  float* E    = (float*)(ws + OFF_E);
  bf16*  P    = (bf16*)(ws + OFF_Q);      // reuse Q+K region after QK^T
  float* pv0  = (float*)(ws + OFF_ATTN);  // PV part 0
  float* pv1  = (float*)(ws + OFF_E);     // PV part 1 (E dead after softmax)
  bf16*  T1   = (bf16*)(ws + OFF_E);      // FF1 out (pv1 dead after LN1)
  float* ff0  = (float*)(ws + OFF_ATTN);  // FF2 part 0
  float* ff1  = (float*)(ws + OFF_Q);     // FF2 part 1 (P dead after PV)
  float* h    = (float*)(ws + OFF_H);
  bf16*  hb   = (bf16*)(ws + OFF_XPE_B);
  bf16*  WqkvT = (bf16*)(ws + OFF_WQKVT);
  bf16*  W1T  = (bf16*)(ws + OFF_W1T);
  bf16*  W2T  = (bf16*)(ws + OFF_W2T);

  const long long sOk_pv = (long long)(OFF_E / 4) - (long long)(OFF_ATTN / 4);
  const long long sOk_ff = (long long)(OFF_Q / 4) - (long long)(OFF_ATTN / 4);

  const dim3 tb(32, 8);
  transpose_kernel<<<dim3(EMBED / 32, EMBED / 32), tb, 0, stream>>>(Wq, WqkvT, EMBED, EMBED);
  transpose_kernel<<<dim3(EMBED / 32, EMBED / 32), tb, 0, stream>>>(Wk, WqkvT + (size_t)EMBED * EMBED, EMBED, EMBED);
  transpose_kernel<<<dim3(EMBED / 32, EMBED / 32), tb, 0, stream>>>(Wv, WqkvT + 2ull * EMBED * EMBED, EMBED, EMBED);
  transpose_kernel<<<dim3(FFDIM / 32, EMBED / 32), tb, 0, stream>>>(W1, W1T, EMBED, FFDIM);
  transpose_kernel<<<dim3(EMBED / 32, FFDIM / 32), tb, 0, stream>>>(W2, W2T, FFDIM, EMBED);

  pe_add_kernel<<<(SEQ * 512) / 256, 256, 0, stream>>>(x, xpe, xpeb);

  // fused QKV (384 blocks)
  gemm8_kernel<6><<<dim3(3072 / BNX, MTOK / BMX, 1), 512, 0, stream>>>(
      xpeb, WqkvT, bq, Qb, EMBED, EMBED, EMBED, EMBED, 1,
      0, 0, 0, 0, 0, 0, 1.0f, bk, bv, Kb, VT);

  // QK^T: E = Q @ K^T / 32  (256 blocks)
  gemm8_kernel<2><<<dim3(SEQ / BNX, SEQ / BMX, BATCH), 512, 0, stream>>>(
      Qb, Kb, nullptr, E, EMBED, EMBED, EMBED, SEQ, BATCH,
      (long long)SEQ * EMBED, (long long)SEQ * EMBED, (long long)SEQ * SEQ,
      0, 0, 0, 0.03125f, nullptr, nullptr, nullptr, nullptr);

  softmax_kernel<<<BATCH * SEQ, 256, 0, stream>>>(E, P);

  // PV split-K: K=2048 -> 2x1024 (256 blocks)
  gemm8_kernel<2><<<dim3(EMBED / BNX, SEQ / BMX, BATCH * 2), 512, 0, stream>>>(
      P, VT, nullptr, pv0, 1024, SEQ, SEQ, EMBED, BATCH,
      (long long)SEQ * SEQ, (long long)EMBED * SEQ, (long long)SEQ * EMBED,
      1024, 1024, sOk_pv,
      1.0f, nullptr, nullptr, nullptr, nullptr);

  // h = LN(pv0 + pv1 + xpe)
  ln_kernel<<<MTOK, 256, 0, stream>>>(pv0, pv1, xpe, nullptr, g1, be1, h, hb);

  // FF1: relu(h @ W1 + b1)  (512 blocks)
  gemm8_kernel<3><<<dim3(FFDIM / BNX, MTOK / BMX, 1), 512, 0, stream>>>(
      hb, W1T, b1, T1, EMBED, EMBED, EMBED, FFDIM, 1,
      0, 0, 0, 0, 0, 0, 1.0f, nullptr, nullptr, nullptr, nullptr);

  // FF2 split-K: K=4096 -> 2x2048 (256 blocks); bias folded into LN2
  gemm8_kernel<2><<<dim3(EMBED / BNX, MTOK / BMX, 2), 512, 0, stream>>>(
      T1, W2T, nullptr, ff0, 2048, FFDIM, FFDIM, EMBED, 1,
      0, 0, 0,
      2048, 2048, sOk_ff,
      1.0f, nullptr, nullptr, nullptr, nullptr);

  // out = LN(ff0 + ff1 + b2 + h)
  ln_kernel<<<MTOK, 256, 0, stream>>>(ff0, ff1, h, b2, g2, be2, out, nullptr);
}

// Round 12
// 375.292 us; speedup vs baseline: 1.1631x; 1.0555x over previous
//
#include <hip/hip_runtime.h>
#include <hip/hip_bf16.h>
#include <cmath>
#include <cstdint>

typedef __bf16 bf16;
typedef __bf16 bf16x8 __attribute__((ext_vector_type(8)));
typedef __bf16 bf16x4 __attribute__((ext_vector_type(4)));
typedef float  f32x4  __attribute__((ext_vector_type(4)));

#define EMBED 1024
#define FFDIM 4096
#define BATCH 4
#define SEQ   2048
#define MTOK  (BATCH*SEQ)

// ---------------- workspace layout ----------------
// 0..16MB: hb (bf16, written by LN1, read by FF1+LN2) — was aliased at 48MB in r10/r11 (BUG)
static constexpr size_t OFF_HB    = 0;
static constexpr size_t OFF_XPE_B = 32ull << 20;    // 16MB bf16 xpeb (live to LN1)
static constexpr size_t OFF_Q     = 48ull << 20;    // 16MB bf16; Q..K reused as P (32MB); then ff1
static constexpr size_t OFF_K     = 64ull << 20;
static constexpr size_t OFF_VT    = 80ull << 20;    // 16MB bf16 [4][1024][2048]
static constexpr size_t OFF_E     = 96ull << 20;    // 32MB bf16 E; then pv1 f32; then T1 bf16 (64MB)
static constexpr size_t OFF_ATTN  = 160ull << 20;   // 16MB Vb; then pv0 f32 32MB; then ff0
static constexpr size_t OFF_WQKVT = 224ull << 20;   // 6MB bf16 [3072][1024]
static constexpr size_t OFF_W1T   = 230ull << 20;   // 8MB
static constexpr size_t OFF_W2T   = 238ull << 20;   // 8MB

// ---------------- wait/barrier primitives (round-9 proven set) ----------------
#define VMCNT4 { asm volatile("s_waitcnt vmcnt(4)" ::: "memory"); __builtin_amdgcn_sched_barrier(0); }
#define VMCNT0 { asm volatile("s_waitcnt vmcnt(0)" ::: "memory"); __builtin_amdgcn_sched_barrier(0); }
// pre-MFMA fence: barrier then per-wave lgkm drain
#define PH_BAR  { __builtin_amdgcn_sched_barrier(0); __builtin_amdgcn_s_barrier(); \
                  asm volatile("s_waitcnt lgkmcnt(0)" ::: "memory"); __builtin_amdgcn_sched_barrier(0); }
// order pin after an MFMA cluster
#define PH_END  { __builtin_amdgcn_sched_barrier(0); }
// plain block barrier
#define BARONLY { __builtin_amdgcn_sched_barrier(0); __builtin_amdgcn_s_barrier(); \
                  __builtin_amdgcn_sched_barrier(0); }

__device__ __forceinline__ void gload_lds16(const void* g, void* l) {
  __builtin_amdgcn_global_load_lds((const __attribute__((address_space(1))) void*)g,
                                   (__attribute__((address_space(3))) void*)l, 16, 0, 0);
}

// ---------------- PE add: xb = bf16(x + pe) ----------------
__global__ __launch_bounds__(256) void pe_add_kernel(const float* __restrict__ x,
                                                     bf16* __restrict__ xb) {
  int idx  = blockIdx.x * 256 + threadIdx.x;
  int pair = idx & 511;
  int s    = idx >> 9;
  float div = __expf((float)(2 * pair) * (-9.210340371976184f / (float)EMBED));
  float ang = (float)s * div;
  float sv = sinf(ang), cv = cosf(ang);
#pragma unroll
  for (int b = 0; b < BATCH; ++b) {
    size_t base = ((size_t)(b * SEQ + s)) * EMBED + (size_t)pair * 2;
    xb[base]     = (bf16)(x[base] + sv);
    xb[base + 1] = (bf16)(x[base + 1] + cv);
  }
}

// ---------------- weight transpose fp32[K][N] -> bf16[N][K] ----------------
__global__ __launch_bounds__(256) void transpose_kernel(const float* __restrict__ W,
                                                        bf16* __restrict__ Wt,
                                                        int K, int N) {
  __shared__ float tile[32][33];
  int nb = blockIdx.x * 32, kb = blockIdx.y * 32;
  int tx = threadIdx.x, ty = threadIdx.y;   // 32x8
#pragma unroll
  for (int i = 0; i < 32; i += 8)
    tile[ty + i][tx] = W[(size_t)(kb + ty + i) * N + nb + tx];
  __syncthreads();
#pragma unroll
  for (int i = 0; i < 32; i += 8)
    Wt[(size_t)(nb + ty + i) * K + kb + tx] = (bf16)tile[tx][ty + i];
}

// ---------------- V transpose bf16 [b][s][d] -> [b][d][s] ----------------
__global__ __launch_bounds__(256) void vtrans_kernel(const bf16* __restrict__ V,
                                                     bf16* __restrict__ VT) {
  __shared__ ushort tile[32][36];
  const int d0 = blockIdx.x * 32, s0 = blockIdx.y * 32, b = blockIdx.z;
  const ushort* src = (const ushort*)V + ((size_t)b * SEQ + s0) * EMBED + d0;
  ushort* dst = (ushort*)VT + ((size_t)b * EMBED + d0) * SEQ + s0;
  const int tx = threadIdx.x, ty = threadIdx.y;   // 32x8
#pragma unroll
  for (int i = 0; i < 32; i += 8)
    tile[ty + i][tx] = src[(size_t)(ty + i) * EMBED + tx];
  __syncthreads();
#pragma unroll
  for (int i = 0; i < 32; i += 8)
    dst[(size_t)(ty + i) * SEQ + tx] = tile[tx][ty + i];
}

// ---------------- gemm8: 256x256 tile, 8 waves (2Mx4N), 8-phase counted-vmcnt ----------------
// LDS 128KB: A[2buf][2qr][2wm][64][64], B[2buf][2qc][4wn][32][64], XOR-swizzled.
// Round-9 proven sync structure (PH_BAR pre-MFMA; vmcnt(4) at P4/P8 only).
// EPI 2: f32 *scale (+split-K)  EPI 5: bf16 *scale  EPI 3: bf16 +bias relu
// EPI 6: fused QKV, all row-major +bias
#define BMX 256
#define BNX 256
#define BKX 64

#define MM16(QR, QC, FB) { \
  __builtin_amdgcn_s_setprio(1); \
  _Pragma("unroll") for (int kk = 0; kk < 2; ++kk) \
  _Pragma("unroll") for (int i2 = 0; i2 < 4; ++i2) \
  _Pragma("unroll") for (int j2 = 0; j2 < 2; ++j2) \
    acc[(QR)*4 + i2][(QC)*2 + j2] = __builtin_amdgcn_mfma_f32_16x16x32_bf16( \
        fa[kk][i2], FB[kk][j2], acc[(QR)*4 + i2][(QC)*2 + j2], 0, 0, 0); \
  __builtin_amdgcn_s_setprio(0); }

template <int EPI>
__global__ __launch_bounds__(512, 2) void gemm8_kernel(
    const bf16* __restrict__ A, const bf16* __restrict__ B,
    const float* __restrict__ bias, void* __restrict__ out,
    int K, int lda, int ldb, int ldo, int NB,
    long long sAz, long long sBz, long long sOz,
    long long sAk, long long sBk, long long sOk,
    float scale,
    const float* bias2, const float* bias3, void* out2, void* out3) {
  __shared__ __align__(16) char ldsA[2 * 32768];
  __shared__ __align__(16) char ldsB[2 * 32768];

  // T1: bijective XCD-chunked swizzle + grouped raster (G=8)
  const int gx = gridDim.x, gy = gridDim.y;
  int id = blockIdx.x + gx * (blockIdx.y + gy * blockIdx.z);
  const int nwg = gx * gy * gridDim.z;
  const int qd = nwg >> 3, rm = nwg & 7;
  const int xcd = id & 7, pos = id >> 3;
  const int lid = (xcd < rm ? xcd * (qd + 1) : rm * (qd + 1) + (xcd - rm) * qd) + pos;
  const int per = gx * gy;
  const int tz = lid / per;
  const int s2 = lid - tz * per;
  const int G = 8;
  const int ngrp = G * gy;
  const int grp = s2 / ngrp;
  const int within = s2 - grp * ngrp;
  const int gwf = gx - grp * G;
  const int gw = gwf < G ? gwf : G;
  const int tx = grp * G + within % gw;
  const int ty = within / gw;

  const int zb = tz % NB;
  const int kh = tz / NB;
  A += (long long)zb * sAz + (long long)kh * sAk;
  B += (long long)zb * sBz + (long long)kh * sBk;

  const int tid  = threadIdx.x;
  const int wave = tid >> 6;
  const int lane = tid & 63;
  const int wm = wave >> 2, wn = wave & 3;   // 2M x 4N
  const int rowBase = ty * BMX;
  const int colBase = tx * BNX;
  const int lr = lane & 15;
  const int g  = lane >> 4;
  const int lx = lr & 7;

  // staging: thread t -> rr = t>>3, slot (t&7)^(rr&7) (src pre-swizzled, rule 21)
  const int rr = tid >> 3;
  const int slot = (tid & 7) ^ (rr & 7);
  const bf16* Abase = A + (long long)(rowBase + rr) * lda + slot * 8;
  const bf16* Bb0 = B + (long long)(colBase + (rr & 31) + ((rr >> 5)) * 64) * ldb + slot * 8;
  const bf16* Bb1 = B + (long long)(colBase + (rr & 31) + (2 + (rr >> 5)) * 64) * ldb + slot * 8;

  auto stA = [&](int T, int bufOff, int qr) {
    char* dst = ldsA + bufOff + qr * 16384 + wave * 1024;
    const bf16* s = Abase + (long long)(qr * 64) * lda + (long long)T * BKX;
    gload_lds16(s, dst);
    gload_lds16(s + (long long)128 * lda, dst + 8192);
  };
  auto stB = [&](int T, int bufOff, int qc) {
    char* dst = ldsB + bufOff + qc * 16384 + wave * 1024;
    const long long off = (long long)(qc * 32) * ldb + (long long)T * BKX;
    gload_lds16(Bb0 + off, dst);
    gload_lds16(Bb1 + off, dst + 8192);
  };

  bf16x8 fa[2][4], fbq0[2][2], fbq1[2][2];
  auto rdFA = [&](int bufOff, int qr) {
    const char* base = ldsA + bufOff + qr * 16384 + wm * 8192;
#pragma unroll
    for (int kk = 0; kk < 2; ++kk) {
      const int sw = ((kk * 4 + g) ^ lx) << 4;
#pragma unroll
      for (int i2 = 0; i2 < 4; ++i2)
        fa[kk][i2] = *(const bf16x8*)(base + (i2 * 16 + lr) * 128 + sw);
    }
  };
  auto rdFB = [&](int bufOff, int qc, bf16x8 fb[2][2]) {
    const char* base = ldsB + bufOff + qc * 16384 + wn * 4096;
#pragma unroll
    for (int kk = 0; kk < 2; ++kk) {
      const int sw = ((kk * 4 + g) ^ lx) << 4;
#pragma unroll
      for (int j2 = 0; j2 < 2; ++j2)
        fb[kk][j2] = *(const bf16x8*)(base + (j2 * 16 + lr) * 128 + sw);
    }
  };

  const f32x4 zero4 = {0.f, 0.f, 0.f, 0.f};
  f32x4 acc[8][4];
#pragma unroll
  for (int i = 0; i < 8; ++i)
#pragma unroll
    for (int j = 0; j < 4; ++j) acc[i][j] = zero4;

  const int nK = K / BKX;   // even (>= 16) for all launches here

  // prologue: tile0 (4 halves) + tile1 hA0,hB0; drain tile0 (leave 4 in flight)
  stA(0, 0, 0); stB(0, 0, 0); stA(0, 0, 1); stB(0, 0, 1);
  stA(1, 32768, 0); stB(1, 32768, 0);
  VMCNT4;
  __builtin_amdgcn_s_barrier(); __builtin_amdgcn_sched_barrier(0);

  // stage schedule (verified ledger, rounds 8-11):
  //   P1 hA1(T0+1) P2 hB1(T0+1) P3 hA0(T0+2) P4 hB0(T0+2)
  //   P5 hA1(T0+2) P6 hB1(T0+2) P7 hA0(T0+3) P8 hB0(T0+3)
  //   vmcnt(4) at P4/P8 ends only.
#define STEP(STG) { \
    rdFA(0, 0); rdFB(0, 0, fbq0); stA(T0 + 1, 32768, 1);              /* P1 */ \
    PH_BAR; MM16(0, 0, fbq0); PH_END; \
    rdFB(0, 1, fbq1); stB(T0 + 1, 32768, 1);                          /* P2 */ \
    PH_BAR; MM16(0, 1, fbq1); PH_END; \
    rdFA(0, 1); if (STG) stA(T0 + 2, 0, 0);                           /* P3 */ \
    PH_BAR; MM16(1, 0, fbq0); PH_END; \
    if (STG) stB(T0 + 2, 0, 0);                                       /* P4 */ \
    MM16(1, 1, fbq1); \
    if (STG) { VMCNT4 } else { VMCNT0 } \
    BARONLY; \
    rdFA(32768, 0); rdFB(32768, 0, fbq0); if (STG) stA(T0 + 2, 0, 1); /* P5 */ \
    PH_BAR; MM16(0, 0, fbq0); PH_END; \
    rdFB(32768, 1, fbq1); if (STG) stB(T0 + 2, 0, 1);                 /* P6 */ \
    PH_BAR; MM16(0, 1, fbq1); PH_END; \
    rdFA(32768, 1); if (STG) stA(T0 + 3, 32768, 0);                   /* P7 */ \
    PH_BAR; MM16(1, 0, fbq0); PH_END; \
    if (STG) stB(T0 + 3, 32768, 0);                                   /* P8 */ \
    MM16(1, 1, fbq1); \
    if (STG) { VMCNT4 } \
    BARONLY; \
  }

  int T0 = 0;
  for (; T0 + 2 < nK; T0 += 2) STEP(1);
  STEP(0);
#undef STEP

  // epilogue: C/D col = lane&15, row = (lane>>4)*4 + reg [m89]; quadrant remap.
#pragma unroll
  for (int j = 0; j < 4; ++j) {
    const int col = colBase + wn * 64 + (j >> 1) * 32 + (j & 1) * 16 + lr;
#pragma unroll
    for (int i = 0; i < 8; ++i) {
      const int row0 = rowBase + wm * 128 + (i >> 2) * 64 + (i & 3) * 16 + g * 4;
      if constexpr (EPI == 6) {
        const int cb = col >> 10;        // uniform per block (colBase mult of 256)
        const int c  = col & 1023;
        const float bv = (cb == 0 ? bias : (cb == 1 ? bias2 : bias3))[c];
        bf16* dst = (cb == 0 ? (bf16*)out : (cb == 1 ? (bf16*)out2 : (bf16*)out3));
#pragma unroll
        for (int rr2 = 0; rr2 < 4; ++rr2)
          dst[(size_t)(row0 + rr2) * EMBED + c] = (bf16)(acc[i][j][rr2] + bv);
      } else if constexpr (EPI == 2) {
        float* dst = (float*)out + (long long)zb * sOz + (long long)kh * sOk;
#pragma unroll
        for (int rr2 = 0; rr2 < 4; ++rr2)
          dst[(long long)(row0 + rr2) * ldo + col] = acc[i][j][rr2] * scale;
      } else if constexpr (EPI == 5) {
        bf16* dst = (bf16*)out + (long long)zb * sOz;
#pragma unroll
        for (int rr2 = 0; rr2 < 4; ++rr2)
          dst[(long long)(row0 + rr2) * ldo + col] = (bf16)(acc[i][j][rr2] * scale);
      } else if constexpr (EPI == 3) {
        const float bv = bias[col];
#pragma unroll
        for (int rr2 = 0; rr2 < 4; ++rr2) {
          float t = acc[i][j][rr2] + bv;
          ((bf16*)out)[(size_t)(row0 + rr2) * ldo + col] = (bf16)(t > 0.f ? t : 0.f);
        }
      }
    }
  }
}

// ---------------- row softmax: E bf16 [rows][SEQ] -> P bf16 ----------------
__global__ __launch_bounds__(256) void softmax_kernel(const bf16* __restrict__ E,
                                                      bf16* __restrict__ P) {
  const size_t row = blockIdx.x;
  const int t = threadIdx.x;
  bf16x8 ev = *(const bf16x8*)(E + row * SEQ + (size_t)t * 8);
  float e[8];
#pragma unroll
  for (int q = 0; q < 8; ++q) e[q] = (float)ev[q];
  float m = e[0];
#pragma unroll
  for (int q = 1; q < 8; ++q) m = fmaxf(m, e[q]);
#pragma unroll
  for (int o = 32; o; o >>= 1) m = fmaxf(m, __shfl_xor(m, o));
  __shared__ float red[8];
  const int w = t >> 6;
  if ((t & 63) == 0) red[w] = m;
  __syncthreads();
  m = fmaxf(fmaxf(red[0], red[1]), fmaxf(red[2], red[3]));
  float s = 0.f;
#pragma unroll
  for (int q = 0; q < 8; ++q) { e[q] = __expf(e[q] - m); s += e[q]; }
#pragma unroll
  for (int o = 32; o; o >>= 1) s += __shfl_xor(s, o);
  if ((t & 63) == 0) red[4 + w] = s;
  __syncthreads();
  s = red[4] + red[5] + red[6] + red[7];
  const float inv = 1.0f / s;
  bf16x8 pv;
#pragma unroll
  for (int q = 0; q < 8; ++q) pv[q] = (bf16)(e[q] * inv);
  *(bf16x8*)(P + row * SEQ + (size_t)t * 8) = pv;
}

// ---------------- LayerNorm: out = LN(X [+X2] [+cb] + Rb) * g + b ----------------
__global__ __launch_bounds__(256) void ln_kernel(const float* __restrict__ X,
                                                 const float* __restrict__ X2,
                                                 const bf16* __restrict__ Rb,
                                                 const float* __restrict__ cb,
                                                 const float* __restrict__ gm,
                                                 const float* __restrict__ bt,
                                                 float* __restrict__ of,
                                                 bf16* __restrict__ ob) {
  const size_t row = blockIdx.x;
  const int t = threadIdx.x;
  float4 xv = ((const float4*)(X + row * EMBED))[t];
  bf16x4 rv = *(const bf16x4*)(Rb + row * EMBED + (size_t)t * 4);
  float4 v;
  v.x = xv.x + (float)rv[0]; v.y = xv.y + (float)rv[1];
  v.z = xv.z + (float)rv[2]; v.w = xv.w + (float)rv[3];
  if (X2) {
    float4 x2 = ((const float4*)(X2 + row * EMBED))[t];
    v.x += x2.x; v.y += x2.y; v.z += x2.z; v.w += x2.w;
  }
  if (cb) {
    float4 c4 = ((const float4*)cb)[t];
    v.x += c4.x; v.y += c4.y; v.z += c4.z; v.w += c4.w;
  }
  float s  = v.x + v.y + v.z + v.w;
  float ss = v.x * v.x + v.y * v.y + v.z * v.z + v.w * v.w;
#pragma unroll
  for (int o = 32; o; o >>= 1) { s += __shfl_xor(s, o); ss += __shfl_xor(ss, o); }
  __shared__ float red[8];
  const int w = t >> 6;
  if ((t & 63) == 0) { red[w] = s; red[4 + w] = ss; }
  __syncthreads();
  s  = red[0] + red[1] + red[2] + red[3];
  ss = red[4] + red[5] + red[6] + red[7];
  const float mu  = s * (1.0f / EMBED);
  const float inv = rsqrtf(ss * (1.0f / EMBED) - mu * mu + 1e-5f);
  float4 gv = ((const float4*)gm)[t];
  float4 bv = ((const float4*)bt)[t];
  float4 o4;
  o4.x = (v.x - mu) * inv * gv.x + bv.x;
  o4.y = (v.y - mu) * inv * gv.y + bv.y;
  o4.z = (v.z - mu) * inv * gv.z + bv.z;
  o4.w = (v.w - mu) * inv * gv.w + bv.w;
  if (of) ((float4*)(of + row * EMBED))[t] = o4;
  if (ob) {
    bf16x4 p;
    p[0] = (bf16)o4.x; p[1] = (bf16)o4.y; p[2] = (bf16)o4.z; p[3] = (bf16)o4.w;
    *(bf16x4*)(ob + row * EMBED + (size_t)t * 4) = p;
  }
}

// ---------------- launch ----------------
extern "C" void kernel_launch(void* const* d_in, const int* in_sizes, int n_in,
                              void* d_out, int out_size, void* d_ws, size_t ws_size,
                              hipStream_t stream) {
  const float* x   = (const float*)d_in[0];
  const float* Wq  = (const float*)d_in[1];
  const float* bq  = (const float*)d_in[2];
  const float* Wk  = (const float*)d_in[3];
  const float* bk  = (const float*)d_in[4];
  const float* Wv  = (const float*)d_in[5];
  const float* bv  = (const float*)d_in[6];
  const float* W1  = (const float*)d_in[7];
  const float* b1  = (const float*)d_in[8];
  const float* W2  = (const float*)d_in[9];
  const float* b2  = (const float*)d_in[10];
  const float* g1  = (const float*)d_in[11];
  const float* be1 = (const float*)d_in[12];
  const float* g2  = (const float*)d_in[13];
  const float* be2 = (const float*)d_in[14];
  float* out = (float*)d_out;
  char* ws = (char*)d_ws;

  bf16*  hb   = (bf16*)(ws + OFF_HB);     // 0..16MB — no aliasing
  bf16*  xpeb = (bf16*)(ws + OFF_XPE_B);
  bf16*  Qb   = (bf16*)(ws + OFF_Q);
  bf16*  Kb   = (bf16*)(ws + OFF_K);
  bf16*  VT   = (bf16*)(ws + OFF_VT);
  bf16*  Vb   = (bf16*)(ws + OFF_ATTN);   // row-major V (dead after vtrans)
  bf16*  E    = (bf16*)(ws + OFF_E);      // 32MB bf16
  bf16*  P    = (bf16*)(ws + OFF_Q);      // reuse Q+K region after QK^T
  float* pv0  = (float*)(ws + OFF_ATTN);  // PV part 0 (Vb dead)
  float* pv1  = (float*)(ws + OFF_E);     // PV part 1 (E dead after softmax)
  bf16*  T1   = (bf16*)(ws + OFF_E);      // FF1 out (pv1 dead after LN1)
  float* ff0  = (float*)(ws + OFF_ATTN);  // FF2 part 0 (pv0 dead)
  float* ff1  = (float*)(ws + OFF_Q);     // FF2 part 1 (P dead)
  bf16*  WqkvT = (bf16*)(ws + OFF_WQKVT);
  bf16*  W1T  = (bf16*)(ws + OFF_W1T);
  bf16*  W2T  = (bf16*)(ws + OFF_W2T);

  const long long sOk_pv = (long long)(OFF_E / 4) - (long long)(OFF_ATTN / 4);
  const long long sOk_ff = (long long)(OFF_Q / 4) - (long long)(OFF_ATTN / 4);

  const dim3 tb(32, 8);
  transpose_kernel<<<dim3(EMBED / 32, EMBED / 32), tb, 0, stream>>>(Wq, WqkvT, EMBED, EMBED);
  transpose_kernel<<<dim3(EMBED / 32, EMBED / 32), tb, 0, stream>>>(Wk, WqkvT + (size_t)EMBED * EMBED, EMBED, EMBED);
  transpose_kernel<<<dim3(EMBED / 32, EMBED / 32), tb, 0, stream>>>(Wv, WqkvT + 2ull * EMBED * EMBED, EMBED, EMBED);
  transpose_kernel<<<dim3(FFDIM / 32, EMBED / 32), tb, 0, stream>>>(W1, W1T, EMBED, FFDIM);
  transpose_kernel<<<dim3(EMBED / 32, FFDIM / 32), tb, 0, stream>>>(W2, W2T, FFDIM, EMBED);

  pe_add_kernel<<<(SEQ * 512) / 256, 256, 0, stream>>>(x, xpeb);

  // fused QKV, all row-major (384 blocks)
  gemm8_kernel<6><<<dim3(3072 / BNX, MTOK / BMX, 1), 512, 0, stream>>>(
      xpeb, WqkvT, bq, Qb, EMBED, EMBED, EMBED, EMBED, 1,
      0, 0, 0, 0, 0, 0, 1.0f, bk, bv, Kb, Vb);

  // V -> VT (coalesced LDS transpose)
  vtrans_kernel<<<dim3(EMBED / 32, SEQ / 32, BATCH), tb, 0, stream>>>(Vb, VT);

  // QK^T: E = bf16(Q @ K^T / 32)  (256 blocks)
  gemm8_kernel<5><<<dim3(SEQ / BNX, SEQ / BMX, BATCH), 512, 0, stream>>>(
      Qb, Kb, nullptr, E, EMBED, EMBED, EMBED, SEQ, BATCH,
      (long long)SEQ * EMBED, (long long)SEQ * EMBED, (long long)SEQ * SEQ,
      0, 0, 0, 0.03125f, nullptr, nullptr, nullptr, nullptr);

  softmax_kernel<<<BATCH * SEQ, 256, 0, stream>>>(E, P);

  // PV split-K: K=2048 -> 2x1024 (256 blocks)
  gemm8_kernel<2><<<dim3(EMBED / BNX, SEQ / BMX, BATCH * 2), 512, 0, stream>>>(
      P, VT, nullptr, pv0, 1024, SEQ, SEQ, EMBED, BATCH,
      (long long)SEQ * SEQ, (long long)EMBED * SEQ, (long long)SEQ * EMBED,
      1024, 1024, sOk_pv,
      1.0f, nullptr, nullptr, nullptr, nullptr);

  // hb = bf16(LN(pv0 + pv1 + xpeb))
  ln_kernel<<<MTOK, 256, 0, stream>>>(pv0, pv1, xpeb, nullptr, g1, be1, nullptr, hb);

  // FF1: relu(hb @ W1 + b1)  (512 blocks)
  gemm8_kernel<3><<<dim3(FFDIM / BNX, MTOK / BMX, 1), 512, 0, stream>>>(
      hb, W1T, b1, T1, EMBED, EMBED, EMBED, FFDIM, 1,
      0, 0, 0, 0, 0, 0, 1.0f, nullptr, nullptr, nullptr, nullptr);

  // FF2 split-K: K=4096 -> 2x2048 (256 blocks); bias folded into LN2
  gemm8_kernel<2><<<dim3(EMBED / BNX, MTOK / BMX, 2), 512, 0, stream>>>(
      T1, W2T, nullptr, ff0, 2048, FFDIM, FFDIM, EMBED, 1,
      0, 0, 0,
      2048, 2048, sOk_ff,
      1.0f, nullptr, nullptr, nullptr, nullptr);

  // out = LN(ff0 + ff1 + b2 + hb)
  ln_kernel<<<MTOK, 256, 0, stream>>>(ff0, ff1, hb, b2, g2, be2, out, nullptr);
}

// Round 13
// 362.215 us; speedup vs baseline: 1.2051x; 1.0361x over previous
//
#include <hip/hip_runtime.h>
#include <hip/hip_bf16.h>
#include <cmath>
#include <cstdint>

typedef __bf16 bf16;
typedef __bf16 bf16x8 __attribute__((ext_vector_type(8)));
typedef __bf16 bf16x4 __attribute__((ext_vector_type(4)));
typedef float  f32x4  __attribute__((ext_vector_type(4)));

#define EMBED 1024
#define FFDIM 4096
#define BATCH 4
#define SEQ   2048
#define MTOK  (BATCH*SEQ)

// ---------------- workspace layout ----------------
// liveness-audited r13: all split-K partials now bf16
static constexpr size_t OFF_HB    = 0;              // 16MB bf16 hb (LN1 w; FF1,LN2 r)
static constexpr size_t OFF_XPE_B = 32ull << 20;    // 16MB bf16 xpeb (PE w; QKV,LN1 r)
static constexpr size_t OFF_Q     = 48ull << 20;    // Qb 16MB; then P 32MB (48-80); then ff1 bf16 16MB
static constexpr size_t OFF_K     = 64ull << 20;
static constexpr size_t OFF_VT    = 80ull << 20;    // 16MB bf16 [4][1024][2048]
static constexpr size_t OFF_E     = 96ull << 20;    // E bf16 32MB (96-128); then pv1 bf16 16MB; then T1 bf16 64MB (96-160)
static constexpr size_t OFF_ATTN  = 160ull << 20;   // Vb 16MB; then pv0 bf16 16MB; then ff0 bf16 16MB
static constexpr size_t OFF_WQKVT = 224ull << 20;   // 6MB bf16 [3072][1024]
static constexpr size_t OFF_W1T   = 230ull << 20;   // 8MB
static constexpr size_t OFF_W2T   = 238ull << 20;   // 8MB

// ---------------- wait/barrier primitives ----------------
#define VMCNT6 { asm volatile("s_waitcnt vmcnt(6)" ::: "memory"); __builtin_amdgcn_sched_barrier(0); }
#define VMCNT8 { asm volatile("s_waitcnt vmcnt(8)" ::: "memory"); __builtin_amdgcn_sched_barrier(0); }
#define VMCNT0 { asm volatile("s_waitcnt vmcnt(0)" ::: "memory"); __builtin_amdgcn_sched_barrier(0); }
// pre-MFMA fence: barrier then per-wave lgkm drain
#define PH_BAR  { __builtin_amdgcn_sched_barrier(0); __builtin_amdgcn_s_barrier(); \
                  asm volatile("s_waitcnt lgkmcnt(0)" ::: "memory"); __builtin_amdgcn_sched_barrier(0); }
// order pin after an MFMA cluster
#define PH_END  { __builtin_amdgcn_sched_barrier(0); }
// plain block barrier
#define BARONLY { __builtin_amdgcn_sched_barrier(0); __builtin_amdgcn_s_barrier(); \
                  __builtin_amdgcn_sched_barrier(0); }

__device__ __forceinline__ void gload_lds16(const void* g, void* l) {
  __builtin_amdgcn_global_load_lds((const __attribute__((address_space(1))) void*)g,
                                   (__attribute__((address_space(3))) void*)l, 16, 0, 0);
}

// ---------------- PE add: xb = bf16(x + pe) ----------------
__global__ __launch_bounds__(256) void pe_add_kernel(const float* __restrict__ x,
                                                     bf16* __restrict__ xb) {
  int idx  = blockIdx.x * 256 + threadIdx.x;
  int pair = idx & 511;
  int s    = idx >> 9;
  float div = __expf((float)(2 * pair) * (-9.210340371976184f / (float)EMBED));
  float ang = (float)s * div;
  float sv = sinf(ang), cv = cosf(ang);
#pragma unroll
  for (int b = 0; b < BATCH; ++b) {
    size_t base = ((size_t)(b * SEQ + s)) * EMBED + (size_t)pair * 2;
    xb[base]     = (bf16)(x[base] + sv);
    xb[base + 1] = (bf16)(x[base + 1] + cv);
  }
}

// ---------------- weight transpose fp32[K][N] -> bf16[N][K] ----------------
__global__ __launch_bounds__(256) void transpose_kernel(const float* __restrict__ W,
                                                        bf16* __restrict__ Wt,
                                                        int K, int N) {
  __shared__ float tile[32][33];
  int nb = blockIdx.x * 32, kb = blockIdx.y * 32;
  int tx = threadIdx.x, ty = threadIdx.y;   // 32x8
#pragma unroll
  for (int i = 0; i < 32; i += 8)
    tile[ty + i][tx] = W[(size_t)(kb + ty + i) * N + nb + tx];
  __syncthreads();
#pragma unroll
  for (int i = 0; i < 32; i += 8)
    Wt[(size_t)(nb + ty + i) * K + kb + tx] = (bf16)tile[tx][ty + i];
}

// ---------------- V transpose bf16 [b][s][d] -> [b][d][s] ----------------
__global__ __launch_bounds__(256) void vtrans_kernel(const bf16* __restrict__ V,
                                                     bf16* __restrict__ VT) {
  __shared__ ushort tile[32][36];
  const int d0 = blockIdx.x * 32, s0 = blockIdx.y * 32, b = blockIdx.z;
  const ushort* src = (const ushort*)V + ((size_t)b * SEQ + s0) * EMBED + d0;
  ushort* dst = (ushort*)VT + ((size_t)b * EMBED + d0) * SEQ + s0;
  const int tx = threadIdx.x, ty = threadIdx.y;   // 32x8
#pragma unroll
  for (int i = 0; i < 32; i += 8)
    tile[ty + i][tx] = src[(size_t)(ty + i) * EMBED + tx];
  __syncthreads();
#pragma unroll
  for (int i = 0; i < 32; i += 8)
    dst[(size_t)(ty + i) * SEQ + tx] = tile[tx][ty + i];
}

// ---------------- gemm8: 256x256 tile, 8 waves (2Mx4N), 8-phase counted-vmcnt ----------------
// LDS 128KB: A[2buf][2qr][2wm][64][64], B[2buf][2qc][4wn][32][64], XOR-swizzled.
// r13: deepened counted-vmcnt {P1:6, P4:8, P5:6, P8:8} — ledger re-derived, never <6 mid-loop.
// EPI 5: bf16 *scale (+batch +split-K)  EPI 3: bf16 +bias relu  EPI 6: fused QKV row-major +bias
#define BMX 256
#define BNX 256
#define BKX 64

#define MM16(QR, QC, FB) { \
  __builtin_amdgcn_s_setprio(1); \
  _Pragma("unroll") for (int kk = 0; kk < 2; ++kk) \
  _Pragma("unroll") for (int i2 = 0; i2 < 4; ++i2) \
  _Pragma("unroll") for (int j2 = 0; j2 < 2; ++j2) \
    acc[(QR)*4 + i2][(QC)*2 + j2] = __builtin_amdgcn_mfma_f32_16x16x32_bf16( \
        fa[kk][i2], FB[kk][j2], acc[(QR)*4 + i2][(QC)*2 + j2], 0, 0, 0); \
  __builtin_amdgcn_s_setprio(0); }

template <int EPI>
__global__ __launch_bounds__(512, 2) void gemm8_kernel(
    const bf16* __restrict__ A, const bf16* __restrict__ B,
    const float* __restrict__ bias, void* __restrict__ out,
    int K, int lda, int ldb, int ldo, int NB,
    long long sAz, long long sBz, long long sOz,
    long long sAk, long long sBk, long long sOk,
    float scale,
    const float* bias2, const float* bias3, void* out2, void* out3) {
  __shared__ __align__(16) char ldsA[2 * 32768];
  __shared__ __align__(16) char ldsB[2 * 32768];

  // T1: bijective XCD-chunked swizzle + grouped raster (G=8)
  const int gx = gridDim.x, gy = gridDim.y;
  int id = blockIdx.x + gx * (blockIdx.y + gy * blockIdx.z);
  const int nwg = gx * gy * gridDim.z;
  const int qd = nwg >> 3, rm = nwg & 7;
  const int xcd = id & 7, pos = id >> 3;
  const int lid = (xcd < rm ? xcd * (qd + 1) : rm * (qd + 1) + (xcd - rm) * qd) + pos;
  const int per = gx * gy;
  const int tz = lid / per;
  const int s2 = lid - tz * per;
  const int G = 8;
  const int ngrp = G * gy;
  const int grp = s2 / ngrp;
  const int within = s2 - grp * ngrp;
  const int gwf = gx - grp * G;
  const int gw = gwf < G ? gwf : G;
  const int tx = grp * G + within % gw;
  const int ty = within / gw;

  const int zb = tz % NB;
  const int kh = tz / NB;
  A += (long long)zb * sAz + (long long)kh * sAk;
  B += (long long)zb * sBz + (long long)kh * sBk;

  const int tid  = threadIdx.x;
  const int wave = tid >> 6;
  const int lane = tid & 63;
  const int wm = wave >> 2, wn = wave & 3;   // 2M x 4N
  const int rowBase = ty * BMX;
  const int colBase = tx * BNX;
  const int lr = lane & 15;
  const int g  = lane >> 4;
  const int lx = lr & 7;

  // staging: thread t -> rr = t>>3, slot (t&7)^(rr&7) (src pre-swizzled, rule 21)
  const int rr = tid >> 3;
  const int slot = (tid & 7) ^ (rr & 7);
  const bf16* Abase = A + (long long)(rowBase + rr) * lda + slot * 8;
  const bf16* Bb0 = B + (long long)(colBase + (rr & 31) + ((rr >> 5)) * 64) * ldb + slot * 8;
  const bf16* Bb1 = B + (long long)(colBase + (rr & 31) + (2 + (rr >> 5)) * 64) * ldb + slot * 8;

  auto stA = [&](int T, int bufOff, int qr) {
    char* dst = ldsA + bufOff + qr * 16384 + wave * 1024;
    const bf16* s = Abase + (long long)(qr * 64) * lda + (long long)T * BKX;
    gload_lds16(s, dst);
    gload_lds16(s + (long long)128 * lda, dst + 8192);
  };
  auto stB = [&](int T, int bufOff, int qc) {
    char* dst = ldsB + bufOff + qc * 16384 + wave * 1024;
    const long long off = (long long)(qc * 32) * ldb + (long long)T * BKX;
    gload_lds16(Bb0 + off, dst);
    gload_lds16(Bb1 + off, dst + 8192);
  };

  bf16x8 fa[2][4], fbq0[2][2], fbq1[2][2];
  auto rdFA = [&](int bufOff, int qr) {
    const char* base = ldsA + bufOff + qr * 16384 + wm * 8192;
#pragma unroll
    for (int kk = 0; kk < 2; ++kk) {
      const int sw = ((kk * 4 + g) ^ lx) << 4;
#pragma unroll
      for (int i2 = 0; i2 < 4; ++i2)
        fa[kk][i2] = *(const bf16x8*)(base + (i2 * 16 + lr) * 128 + sw);
    }
  };
  auto rdFB = [&](int bufOff, int qc, bf16x8 fb[2][2]) {
    const char* base = ldsB + bufOff + qc * 16384 + wn * 4096;
#pragma unroll
    for (int kk = 0; kk < 2; ++kk) {
      const int sw = ((kk * 4 + g) ^ lx) << 4;
#pragma unroll
      for (int j2 = 0; j2 < 2; ++j2)
        fb[kk][j2] = *(const bf16x8*)(base + (j2 * 16 + lr) * 128 + sw);
    }
  };

  const f32x4 zero4 = {0.f, 0.f, 0.f, 0.f};
  f32x4 acc[8][4];
#pragma unroll
  for (int i = 0; i < 8; ++i)
#pragma unroll
    for (int j = 0; j < 4; ++j) acc[i][j] = zero4;

  const int nK = K / BKX;   // even (>= 16) for all launches here

  // prologue: tile0 (4 halves) + tile1 hA0,hB0; drain tile0 (leave 4 in flight)
  stA(0, 0, 0); stB(0, 0, 0); stA(0, 0, 1); stB(0, 0, 1);
  stA(1, 32768, 0); stB(1, 32768, 0);
  { asm volatile("s_waitcnt vmcnt(4)" ::: "memory"); __builtin_amdgcn_sched_barrier(0); }
  __builtin_amdgcn_s_barrier(); __builtin_amdgcn_sched_barrier(0);

  // stage schedule (ledger r13, deepened):
  //   P1 hA1(T0+1) P2 hB1(T0+1) P3 hA0(T0+2) P4 hB0(T0+2)
  //   P5 hA1(T0+2) P6 hB1(T0+2) P7 hA0(T0+3) P8 hB0(T0+3)
  // waits: P1-prep vmcnt(6) [guarantees P6/P7's reads: drains prevP5,prevP6]
  //        P4-end  vmcnt(8) [guarantees P5's reads: drains prevP7,prevP8]
  //        P5-prep vmcnt(6) [guarantees P6/P7's reads: drains P1,P2]
  //        P8-end  vmcnt(8) [guarantees nextP1's reads: drains P3,P4]
#define STEP(STG) { \
    rdFA(0, 0); rdFB(0, 0, fbq0); stA(T0 + 1, 32768, 1);              /* P1 */ \
    VMCNT6; PH_BAR; MM16(0, 0, fbq0); PH_END; \
    rdFB(0, 1, fbq1); stB(T0 + 1, 32768, 1);                          /* P2 */ \
    PH_BAR; MM16(0, 1, fbq1); PH_END; \
    rdFA(0, 1); if (STG) stA(T0 + 2, 0, 0);                           /* P3 */ \
    PH_BAR; MM16(1, 0, fbq0); PH_END; \
    if (STG) stB(T0 + 2, 0, 0);                                       /* P4 */ \
    MM16(1, 1, fbq1); \
    if (STG) { VMCNT8 } else { VMCNT0 } \
    BARONLY; \
    rdFA(32768, 0); rdFB(32768, 0, fbq0); if (STG) stA(T0 + 2, 0, 1); /* P5 */ \
    VMCNT6; PH_BAR; MM16(0, 0, fbq0); PH_END; \
    rdFB(32768, 1, fbq1); if (STG) stB(T0 + 2, 0, 1);                 /* P6 */ \
    PH_BAR; MM16(0, 1, fbq1); PH_END; \
    rdFA(32768, 1); if (STG) stA(T0 + 3, 32768, 0);                   /* P7 */ \
    PH_BAR; MM16(1, 0, fbq0); PH_END; \
    if (STG) stB(T0 + 3, 32768, 0);                                   /* P8 */ \
    MM16(1, 1, fbq1); \
    if (STG) { VMCNT8 } \
    BARONLY; \
  }

  int T0 = 0;
  for (; T0 + 2 < nK; T0 += 2) STEP(1);
  STEP(0);
#undef STEP

  // epilogue: C/D col = lane&15, row = (lane>>4)*4 + reg [m89]; quadrant remap.
#pragma unroll
  for (int j = 0; j < 4; ++j) {
    const int col = colBase + wn * 64 + (j >> 1) * 32 + (j & 1) * 16 + lr;
#pragma unroll
    for (int i = 0; i < 8; ++i) {
      const int row0 = rowBase + wm * 128 + (i >> 2) * 64 + (i & 3) * 16 + g * 4;
      if constexpr (EPI == 6) {
        const int cb = col >> 10;        // uniform per block (colBase mult of 256)
        const int c  = col & 1023;
        const float bv = (cb == 0 ? bias : (cb == 1 ? bias2 : bias3))[c];
        bf16* dst = (cb == 0 ? (bf16*)out : (cb == 1 ? (bf16*)out2 : (bf16*)out3));
#pragma unroll
        for (int rr2 = 0; rr2 < 4; ++rr2)
          dst[(size_t)(row0 + rr2) * EMBED + c] = (bf16)(acc[i][j][rr2] + bv);
      } else if constexpr (EPI == 5) {
        bf16* dst = (bf16*)out + (long long)zb * sOz + (long long)kh * sOk;
#pragma unroll
        for (int rr2 = 0; rr2 < 4; ++rr2)
          dst[(long long)(row0 + rr2) * ldo + col] = (bf16)(acc[i][j][rr2] * scale);
      } else if constexpr (EPI == 3) {
        const float bv = bias[col];
#pragma unroll
        for (int rr2 = 0; rr2 < 4; ++rr2) {
          float t = acc[i][j][rr2] + bv;
          ((bf16*)out)[(size_t)(row0 + rr2) * ldo + col] = (bf16)(t > 0.f ? t : 0.f);
        }
      }
    }
  }
}

// ---------------- row softmax: E bf16 [rows][SEQ] -> P bf16 ----------------
__global__ __launch_bounds__(256) void softmax_kernel(const bf16* __restrict__ E,
                                                      bf16* __restrict__ P) {
  const size_t row = blockIdx.x;
  const int t = threadIdx.x;
  bf16x8 ev = *(const bf16x8*)(E + row * SEQ + (size_t)t * 8);
  float e[8];
#pragma unroll
  for (int q = 0; q < 8; ++q) e[q] = (float)ev[q];
  float m = e[0];
#pragma unroll
  for (int q = 1; q < 8; ++q) m = fmaxf(m, e[q]);
#pragma unroll
  for (int o = 32; o; o >>= 1) m = fmaxf(m, __shfl_xor(m, o));
  __shared__ float red[8];
  const int w = t >> 6;
  if ((t & 63) == 0) red[w] = m;
  __syncthreads();
  m = fmaxf(fmaxf(red[0], red[1]), fmaxf(red[2], red[3]));
  float s = 0.f;
#pragma unroll
  for (int q = 0; q < 8; ++q) { e[q] = __expf(e[q] - m); s += e[q]; }
#pragma unroll
  for (int o = 32; o; o >>= 1) s += __shfl_xor(s, o);
  if ((t & 63) == 0) red[4 + w] = s;
  __syncthreads();
  s = red[4] + red[5] + red[6] + red[7];
  const float inv = 1.0f / s;
  bf16x8 pv;
#pragma unroll
  for (int q = 0; q < 8; ++q) pv[q] = (bf16)(e[q] * inv);
  *(bf16x8*)(P + row * SEQ + (size_t)t * 8) = pv;
}

// ---------------- LayerNorm: out = LN(Xb + X2b [+cb] + Rb) * g + b ----------------
__global__ __launch_bounds__(256) void ln_kernel(const bf16* __restrict__ Xb,
                                                 const bf16* __restrict__ X2b,
                                                 const bf16* __restrict__ Rb,
                                                 const float* __restrict__ cb,
                                                 const float* __restrict__ gm,
                                                 const float* __restrict__ bt,
                                                 float* __restrict__ of,
                                                 bf16* __restrict__ ob) {
  const size_t row = blockIdx.x;
  const int t = threadIdx.x;
  bf16x4 xv = *(const bf16x4*)(Xb + row * EMBED + (size_t)t * 4);
  bf16x4 rv = *(const bf16x4*)(Rb + row * EMBED + (size_t)t * 4);
  float4 v;
  v.x = (float)xv[0] + (float)rv[0];
  v.y = (float)xv[1] + (float)rv[1];
  v.z = (float)xv[2] + (float)rv[2];
  v.w = (float)xv[3] + (float)rv[3];
  if (X2b) {
    bf16x4 x2 = *(const bf16x4*)(X2b + row * EMBED + (size_t)t * 4);
    v.x += (float)x2[0]; v.y += (float)x2[1]; v.z += (float)x2[2]; v.w += (float)x2[3];
  }
  if (cb) {
    float4 c4 = ((const float4*)cb)[t];
    v.x += c4.x; v.y += c4.y; v.z += c4.z; v.w += c4.w;
  }
  float s  = v.x + v.y + v.z + v.w;
  float ss = v.x * v.x + v.y * v.y + v.z * v.z + v.w * v.w;
#pragma unroll
  for (int o = 32; o; o >>= 1) { s += __shfl_xor(s, o); ss += __shfl_xor(ss, o); }
  __shared__ float red[8];
  const int w = t >> 6;
  if ((t & 63) == 0) { red[w] = s; red[4 + w] = ss; }
  __syncthreads();
  s  = red[0] + red[1] + red[2] + red[3];
  ss = red[4] + red[5] + red[6] + red[7];
  const float mu  = s * (1.0f / EMBED);
  const float inv = rsqrtf(ss * (1.0f / EMBED) - mu * mu + 1e-5f);
  float4 gv = ((const float4*)gm)[t];
  float4 bv = ((const float4*)bt)[t];
  float4 o4;
  o4.x = (v.x - mu) * inv * gv.x + bv.x;
  o4.y = (v.y - mu) * inv * gv.y + bv.y;
  o4.z = (v.z - mu) * inv * gv.z + bv.z;
  o4.w = (v.w - mu) * inv * gv.w + bv.w;
  if (of) ((float4*)(of + row * EMBED))[t] = o4;
  if (ob) {
    bf16x4 p;
    p[0] = (bf16)o4.x; p[1] = (bf16)o4.y; p[2] = (bf16)o4.z; p[3] = (bf16)o4.w;
    *(bf16x4*)(ob + row * EMBED + (size_t)t * 4) = p;
  }
}

// ---------------- launch ----------------
extern "C" void kernel_launch(void* const* d_in, const int* in_sizes, int n_in,
                              void* d_out, int out_size, void* d_ws, size_t ws_size,
                              hipStream_t stream) {
  const float* x   = (const float*)d_in[0];
  const float* Wq  = (const float*)d_in[1];
  const float* bq  = (const float*)d_in[2];
  const float* Wk  = (const float*)d_in[3];
  const float* bk  = (const float*)d_in[4];
  const float* Wv  = (const float*)d_in[5];
  const float* bv  = (const float*)d_in[6];
  const float* W1  = (const float*)d_in[7];
  const float* b1  = (const float*)d_in[8];
  const float* W2  = (const float*)d_in[9];
  const float* b2  = (const float*)d_in[10];
  const float* g1  = (const float*)d_in[11];
  const float* be1 = (const float*)d_in[12];
  const float* g2  = (const float*)d_in[13];
  const float* be2 = (const float*)d_in[14];
  float* out = (float*)d_out;
  char* ws = (char*)d_ws;

  bf16*  hb   = (bf16*)(ws + OFF_HB);
  bf16*  xpeb = (bf16*)(ws + OFF_XPE_B);
  bf16*  Qb   = (bf16*)(ws + OFF_Q);
  bf16*  Kb   = (bf16*)(ws + OFF_K);
  bf16*  VT   = (bf16*)(ws + OFF_VT);
  bf16*  Vb   = (bf16*)(ws + OFF_ATTN);   // row-major V (dead after vtrans)
  bf16*  E    = (bf16*)(ws + OFF_E);      // 32MB bf16
  bf16*  P    = (bf16*)(ws + OFF_Q);      // reuse Q+K region after QK^T
  bf16*  pv0  = (bf16*)(ws + OFF_ATTN);   // PV part 0 (Vb dead)
  bf16*  pv1  = (bf16*)(ws + OFF_E);      // PV part 1 (E dead after softmax)
  bf16*  T1   = (bf16*)(ws + OFF_E);      // FF1 out (pv1 dead after LN1)
  bf16*  ff0  = (bf16*)(ws + OFF_ATTN);   // FF2 part 0 (pv0 dead)
  bf16*  ff1  = (bf16*)(ws + OFF_Q);      // FF2 part 1 (P dead)
  bf16*  WqkvT = (bf16*)(ws + OFF_WQKVT);
  bf16*  W1T  = (bf16*)(ws + OFF_W1T);
  bf16*  W2T  = (bf16*)(ws + OFF_W2T);

  // signed bf16-element offsets between split-K output halves
  const long long sOk_pv = ((long long)OFF_E - (long long)OFF_ATTN) / 2;   // pv1 - pv0
  const long long sOk_ff = ((long long)OFF_Q - (long long)OFF_ATTN) / 2;   // ff1 - ff0

  const dim3 tb(32, 8);
  transpose_kernel<<<dim3(EMBED / 32, EMBED / 32), tb, 0, stream>>>(Wq, WqkvT, EMBED, EMBED);
  transpose_kernel<<<dim3(EMBED / 32, EMBED / 32), tb, 0, stream>>>(Wk, WqkvT + (size_t)EMBED * EMBED, EMBED, EMBED);
  transpose_kernel<<<dim3(EMBED / 32, EMBED / 32), tb, 0, stream>>>(Wv, WqkvT + 2ull * EMBED * EMBED, EMBED, EMBED);
  transpose_kernel<<<dim3(FFDIM / 32, EMBED / 32), tb, 0, stream>>>(W1, W1T, EMBED, FFDIM);
  transpose_kernel<<<dim3(EMBED / 32, FFDIM / 32), tb, 0, stream>>>(W2, W2T, FFDIM, EMBED);

  pe_add_kernel<<<(SEQ * 512) / 256, 256, 0, stream>>>(x, xpeb);

  // fused QKV, all row-major (384 blocks)
  gemm8_kernel<6><<<dim3(3072 / BNX, MTOK / BMX, 1), 512, 0, stream>>>(
      xpeb, WqkvT, bq, Qb, EMBED, EMBED, EMBED, EMBED, 1,
      0, 0, 0, 0, 0, 0, 1.0f, bk, bv, Kb, Vb);

  // V -> VT (coalesced LDS transpose)
  vtrans_kernel<<<dim3(EMBED / 32, SEQ / 32, BATCH), tb, 0, stream>>>(Vb, VT);

  // QK^T: E = bf16(Q @ K^T / 32)  (256 blocks)
  gemm8_kernel<5><<<dim3(SEQ / BNX, SEQ / BMX, BATCH), 512, 0, stream>>>(
      Qb, Kb, nullptr, E, EMBED, EMBED, EMBED, SEQ, BATCH,
      (long long)SEQ * EMBED, (long long)SEQ * EMBED, (long long)SEQ * SEQ,
      0, 0, 0, 0.03125f, nullptr, nullptr, nullptr, nullptr);

  softmax_kernel<<<BATCH * SEQ, 256, 0, stream>>>(E, P);

  // PV split-K: K=2048 -> 2x1024, bf16 partials (256 blocks)
  gemm8_kernel<5><<<dim3(EMBED / BNX, SEQ / BMX, BATCH * 2), 512, 0, stream>>>(
      P, VT, nullptr, pv0, 1024, SEQ, SEQ, EMBED, BATCH,
      (long long)SEQ * SEQ, (long long)EMBED * SEQ, (long long)SEQ * EMBED,
      1024, 1024, sOk_pv,
      1.0f, nullptr, nullptr, nullptr, nullptr);

  // hb = bf16(LN(pv0 + pv1 + xpeb))
  ln_kernel<<<MTOK, 256, 0, stream>>>(pv0, pv1, xpeb, nullptr, g1, be1, nullptr, hb);

  // FF1: relu(hb @ W1 + b1)  (512 blocks)
  gemm8_kernel<3><<<dim3(FFDIM / BNX, MTOK / BMX, 1), 512, 0, stream>>>(
      hb, W1T, b1, T1, EMBED, EMBED, EMBED, FFDIM, 1,
      0, 0, 0, 0, 0, 0, 1.0f, nullptr, nullptr, nullptr, nullptr);

  // FF2 split-K: K=4096 -> 2x2048, bf16 partials (256 blocks); bias folded into LN2
  gemm8_kernel<5><<<dim3(EMBED / BNX, MTOK / BMX, 2), 512, 0, stream>>>(
      T1, W2T, nullptr, ff0, 2048, FFDIM, FFDIM, EMBED, 1,
      0, 0, 0,
      2048, 2048, sOk_ff,
      1.0f, nullptr, nullptr, nullptr, nullptr);

  // out = LN(ff0 + ff1 + b2 + hb)
  ln_kernel<<<MTOK, 256, 0, stream>>>(ff0, ff1, hb, b2, g2, be2, out, nullptr);
}

// Round 14
// 331.817 us; speedup vs baseline: 1.3155x; 1.0916x over previous
//
#include <hip/hip_runtime.h>
#include <hip/hip_bf16.h>
#include <cmath>
#include <cstdint>

typedef __bf16 bf16;
typedef __bf16 bf16x8 __attribute__((ext_vector_type(8)));
typedef __bf16 bf16x4 __attribute__((ext_vector_type(4)));
typedef float  f32x4  __attribute__((ext_vector_type(4)));

#define EMBED 1024
#define FFDIM 4096
#define BATCH 4
#define SEQ   2048
#define MTOK  (BATCH*SEQ)

// ---------------- workspace layout ----------------
static constexpr size_t OFF_HB    = 0;              // 16MB bf16 hb (LN1 w; FF1,LN2 r)
static constexpr size_t OFF_XPE_B = 32ull << 20;    // 16MB bf16 xpeb (PE w; QKV,LN1 r)
static constexpr size_t OFF_Q     = 48ull << 20;    // Qb 16MB; then P 32MB (48-80); then ff1 bf16
static constexpr size_t OFF_K     = 64ull << 20;
static constexpr size_t OFF_VT    = 80ull << 20;    // 16MB bf16 [4][1024][2048]
static constexpr size_t OFF_E     = 96ull << 20;    // E bf16 32MB; then pv1 bf16; then T1 bf16 64MB
static constexpr size_t OFF_ATTN  = 160ull << 20;   // Vb 16MB; then pv0 bf16; then ff0 bf16
static constexpr size_t OFF_WQKVT = 224ull << 20;   // 6MB bf16 [3072][1024]
static constexpr size_t OFF_W1T   = 230ull << 20;   // 8MB
static constexpr size_t OFF_W2T   = 238ull << 20;   // 8MB

// ---------------- wait/barrier primitives (round-9 proven set) ----------------
#define VMCNT6 { asm volatile("s_waitcnt vmcnt(6)" ::: "memory"); __builtin_amdgcn_sched_barrier(0); }
#define VMCNT8 { asm volatile("s_waitcnt vmcnt(8)" ::: "memory"); __builtin_amdgcn_sched_barrier(0); }
#define VMCNT0 { asm volatile("s_waitcnt vmcnt(0)" ::: "memory"); __builtin_amdgcn_sched_barrier(0); }
#define PH_BAR  { __builtin_amdgcn_sched_barrier(0); __builtin_amdgcn_s_barrier(); \
                  asm volatile("s_waitcnt lgkmcnt(0)" ::: "memory"); __builtin_amdgcn_sched_barrier(0); }
#define PH_END  { __builtin_amdgcn_sched_barrier(0); }
#define BARONLY { __builtin_amdgcn_sched_barrier(0); __builtin_amdgcn_s_barrier(); \
                  __builtin_amdgcn_sched_barrier(0); }

__device__ __forceinline__ void gload_lds16(const void* g, void* l) {
  __builtin_amdgcn_global_load_lds((const __attribute__((address_space(1))) void*)g,
                                   (__attribute__((address_space(3))) void*)l, 16, 0, 0);
}

// ---------------- PE add: xb = bf16(x + pe) ----------------
__global__ __launch_bounds__(256) void pe_add_kernel(const float* __restrict__ x,
                                                     bf16* __restrict__ xb) {
  int idx  = blockIdx.x * 256 + threadIdx.x;
  int pair = idx & 511;
  int s    = idx >> 9;
  float div = __expf((float)(2 * pair) * (-9.210340371976184f / (float)EMBED));
  float ang = (float)s * div;
  float sv = sinf(ang), cv = cosf(ang);
#pragma unroll
  for (int b = 0; b < BATCH; ++b) {
    size_t base = ((size_t)(b * SEQ + s)) * EMBED + (size_t)pair * 2;
    xb[base]     = (bf16)(x[base] + sv);
    xb[base + 1] = (bf16)(x[base + 1] + cv);
  }
}

// ---------------- weight transpose fp32[K][N] -> bf16[N][K] ----------------
__global__ __launch_bounds__(256) void transpose_kernel(const float* __restrict__ W,
                                                        bf16* __restrict__ Wt,
                                                        int K, int N) {
  __shared__ float tile[32][33];
  int nb = blockIdx.x * 32, kb = blockIdx.y * 32;
  int tx = threadIdx.x, ty = threadIdx.y;   // 32x8
#pragma unroll
  for (int i = 0; i < 32; i += 8)
    tile[ty + i][tx] = W[(size_t)(kb + ty + i) * N + nb + tx];
  __syncthreads();
#pragma unroll
  for (int i = 0; i < 32; i += 8)
    Wt[(size_t)(nb + ty + i) * K + kb + tx] = (bf16)tile[tx][ty + i];
}

// ---------------- V transpose bf16 [b][s][d] -> [b][d][s] ----------------
__global__ __launch_bounds__(256) void vtrans_kernel(const bf16* __restrict__ V,
                                                     bf16* __restrict__ VT) {
  __shared__ ushort tile[32][36];
  const int d0 = blockIdx.x * 32, s0 = blockIdx.y * 32, b = blockIdx.z;
  const ushort* src = (const ushort*)V + ((size_t)b * SEQ + s0) * EMBED + d0;
  ushort* dst = (ushort*)VT + ((size_t)b * EMBED + d0) * SEQ + s0;
  const int tx = threadIdx.x, ty = threadIdx.y;   // 32x8
#pragma unroll
  for (int i = 0; i < 32; i += 8)
    tile[ty + i][tx] = src[(size_t)(ty + i) * EMBED + tx];
  __syncthreads();
#pragma unroll
  for (int i = 0; i < 32; i += 8)
    dst[(size_t)(ty + i) * SEQ + tx] = tile[tx][ty + i];
}

// ---------------- gemm8: 256x256 tile, 8 waves (2Mx4N), 8-phase counted-vmcnt ----------------
// r14: LDS-staged coalesced epilogue (fixes 2.4x write amplification of scalar bf16 stores).
// EPI 5: bf16 *scale (+batch +split-K)  EPI 3: bf16 +bias relu  EPI 6: fused QKV row-major +bias
#define BMX 256
#define BNX 256
#define BKX 64

#define MM16(QR, QC, FB) { \
  __builtin_amdgcn_s_setprio(1); \
  _Pragma("unroll") for (int kk = 0; kk < 2; ++kk) \
  _Pragma("unroll") for (int i2 = 0; i2 < 4; ++i2) \
  _Pragma("unroll") for (int j2 = 0; j2 < 2; ++j2) \
    acc[(QR)*4 + i2][(QC)*2 + j2] = __builtin_amdgcn_mfma_f32_16x16x32_bf16( \
        fa[kk][i2], FB[kk][j2], acc[(QR)*4 + i2][(QC)*2 + j2], 0, 0, 0); \
  __builtin_amdgcn_s_setprio(0); }

template <int EPI>
__global__ __launch_bounds__(512, 2) void gemm8_kernel(
    const bf16* __restrict__ A, const bf16* __restrict__ B,
    const float* __restrict__ bias, void* __restrict__ out,
    int K, int lda, int ldb, int ldo, int NB,
    long long sAz, long long sBz, long long sOz,
    long long sAk, long long sBk, long long sOk,
    float scale,
    const float* bias2, const float* bias3, void* out2, void* out3) {
  __shared__ __align__(16) char ldsbuf[131072];
  char* const ldsA = ldsbuf;            // 2buf x 32KB
  char* const ldsB = ldsbuf + 65536;    // 2buf x 32KB

  // T1: bijective XCD-chunked swizzle + grouped raster (G=8)
  const int gx = gridDim.x, gy = gridDim.y;
  int id = blockIdx.x + gx * (blockIdx.y + gy * blockIdx.z);
  const int nwg = gx * gy * gridDim.z;
  const int qd = nwg >> 3, rm = nwg & 7;
  const int xcd = id & 7, pos = id >> 3;
  const int lid = (xcd < rm ? xcd * (qd + 1) : rm * (qd + 1) + (xcd - rm) * qd) + pos;
  const int per = gx * gy;
  const int tz = lid / per;
  const int s2 = lid - tz * per;
  const int G = 8;
  const int ngrp = G * gy;
  const int grp = s2 / ngrp;
  const int within = s2 - grp * ngrp;
  const int gwf = gx - grp * G;
  const int gw = gwf < G ? gwf : G;
  const int tx = grp * G + within % gw;
  const int ty = within / gw;

  const int zb = tz % NB;
  const int kh = tz / NB;
  A += (long long)zb * sAz + (long long)kh * sAk;
  B += (long long)zb * sBz + (long long)kh * sBk;

  const int tid  = threadIdx.x;
  const int wave = tid >> 6;
  const int lane = tid & 63;
  const int wm = wave >> 2, wn = wave & 3;   // 2M x 4N
  const int rowBase = ty * BMX;
  const int colBase = tx * BNX;
  const int lr = lane & 15;
  const int g  = lane >> 4;
  const int lx = lr & 7;

  // staging: thread t -> rr = t>>3, slot (t&7)^(rr&7) (src pre-swizzled, rule 21)
  const int rr = tid >> 3;
  const int slot = (tid & 7) ^ (rr & 7);
  const bf16* Abase = A + (long long)(rowBase + rr) * lda + slot * 8;
  const bf16* Bb0 = B + (long long)(colBase + (rr & 31) + ((rr >> 5)) * 64) * ldb + slot * 8;
  const bf16* Bb1 = B + (long long)(colBase + (rr & 31) + (2 + (rr >> 5)) * 64) * ldb + slot * 8;

  auto stA = [&](int T, int bufOff, int qr) {
    char* dst = ldsA + bufOff + qr * 16384 + wave * 1024;
    const bf16* s = Abase + (long long)(qr * 64) * lda + (long long)T * BKX;
    gload_lds16(s, dst);
    gload_lds16(s + (long long)128 * lda, dst + 8192);
  };
  auto stB = [&](int T, int bufOff, int qc) {
    char* dst = ldsB + bufOff + qc * 16384 + wave * 1024;
    const long long off = (long long)(qc * 32) * ldb + (long long)T * BKX;
    gload_lds16(Bb0 + off, dst);
    gload_lds16(Bb1 + off, dst + 8192);
  };

  bf16x8 fa[2][4], fbq0[2][2], fbq1[2][2];
  auto rdFA = [&](int bufOff, int qr) {
    const char* base = ldsA + bufOff + qr * 16384 + wm * 8192;
#pragma unroll
    for (int kk = 0; kk < 2; ++kk) {
      const int sw = ((kk * 4 + g) ^ lx) << 4;
#pragma unroll
      for (int i2 = 0; i2 < 4; ++i2)
        fa[kk][i2] = *(const bf16x8*)(base + (i2 * 16 + lr) * 128 + sw);
    }
  };
  auto rdFB = [&](int bufOff, int qc, bf16x8 fb[2][2]) {
    const char* base = ldsB + bufOff + qc * 16384 + wn * 4096;
#pragma unroll
    for (int kk = 0; kk < 2; ++kk) {
      const int sw = ((kk * 4 + g) ^ lx) << 4;
#pragma unroll
      for (int j2 = 0; j2 < 2; ++j2)
        fb[kk][j2] = *(const bf16x8*)(base + (j2 * 16 + lr) * 128 + sw);
    }
  };

  const f32x4 zero4 = {0.f, 0.f, 0.f, 0.f};
  f32x4 acc[8][4];
#pragma unroll
  for (int i = 0; i < 8; ++i)
#pragma unroll
    for (int j = 0; j < 4; ++j) acc[i][j] = zero4;

  const int nK = K / BKX;   // even (>= 16) for all launches here

  // prologue: tile0 (4 halves) + tile1 hA0,hB0; drain tile0 (leave 4 in flight)
  stA(0, 0, 0); stB(0, 0, 0); stA(0, 0, 1); stB(0, 0, 1);
  stA(1, 32768, 0); stB(1, 32768, 0);
  { asm volatile("s_waitcnt vmcnt(4)" ::: "memory"); __builtin_amdgcn_sched_barrier(0); }
  __builtin_amdgcn_s_barrier(); __builtin_amdgcn_sched_barrier(0);

  // stage schedule (verified ledger r13):
  //   P1 hA1(T0+1) P2 hB1(T0+1) P3 hA0(T0+2) P4 hB0(T0+2)
  //   P5 hA1(T0+2) P6 hB1(T0+2) P7 hA0(T0+3) P8 hB0(T0+3)
#define STEP(STG) { \
    rdFA(0, 0); rdFB(0, 0, fbq0); stA(T0 + 1, 32768, 1);              /* P1 */ \
    VMCNT6; PH_BAR; MM16(0, 0, fbq0); PH_END; \
    rdFB(0, 1, fbq1); stB(T0 + 1, 32768, 1);                          /* P2 */ \
    PH_BAR; MM16(0, 1, fbq1); PH_END; \
    rdFA(0, 1); if (STG) stA(T0 + 2, 0, 0);                           /* P3 */ \
    PH_BAR; MM16(1, 0, fbq0); PH_END; \
    if (STG) stB(T0 + 2, 0, 0);                                       /* P4 */ \
    MM16(1, 1, fbq1); \
    if (STG) { VMCNT8 } else { VMCNT0 } \
    BARONLY; \
    rdFA(32768, 0); rdFB(32768, 0, fbq0); if (STG) stA(T0 + 2, 0, 1); /* P5 */ \
    VMCNT6; PH_BAR; MM16(0, 0, fbq0); PH_END; \
    rdFB(32768, 1, fbq1); if (STG) stB(T0 + 2, 0, 1);                 /* P6 */ \
    PH_BAR; MM16(0, 1, fbq1); PH_END; \
    rdFA(32768, 1); if (STG) stA(T0 + 3, 32768, 0);                   /* P7 */ \
    PH_BAR; MM16(1, 0, fbq0); PH_END; \
    if (STG) stB(T0 + 3, 32768, 0);                                   /* P8 */ \
    MM16(1, 1, fbq1); \
    if (STG) { VMCNT8 } \
    BARONLY; \
  }

  int T0 = 0;
  for (; T0 + 2 < nK; T0 += 2) STEP(1);
  STEP(0);
#undef STEP

  // ---- LDS-staged coalesced epilogue ----
  // All waves past final BARONLY; all loads drained (VMCNT0 at tail P4); LDS dead.
  // Swizzle: stored col' = col ^ (((row>>2)&3)<<4). For a store instr, (row>>2)&3 == g
  // (varies per lane) -> 4 row-groups land in disjoint bank octets; conflict-free.
  bf16* ct = (bf16*)ldsbuf;   // [256][256] bf16 = 128KB
#pragma unroll
  for (int j = 0; j < 4; ++j) {
    const int lcol = wn * 64 + (j >> 1) * 32 + (j & 1) * 16 + lr;
    float bv = 0.f;
    if constexpr (EPI == 6) {
      const int gcol = colBase + lcol;
      const int c = gcol & 1023;
      const int cb = gcol >> 10;
      bv = (cb == 0 ? bias : (cb == 1 ? bias2 : bias3))[c];
    } else if constexpr (EPI == 3) {
      bv = bias[colBase + lcol];
    }
#pragma unroll
    for (int i = 0; i < 8; ++i) {
      const int lrow0 = wm * 128 + (i >> 2) * 64 + (i & 3) * 16 + g * 4;
#pragma unroll
      for (int rr2 = 0; rr2 < 4; ++rr2) {
        const int lrow = lrow0 + rr2;
        float v = acc[i][j][rr2];
        if constexpr (EPI == 5) v *= scale;
        else v += bv;
        if constexpr (EPI == 3) v = v > 0.f ? v : 0.f;
        ct[lrow * 256 + (lcol ^ (((lrow >> 2) & 3) << 4))] = (bf16)v;
      }
    }
  }
  __syncthreads();
  // coalesced store: 16 passes, each instr writes two full 512B rows
  bf16* dstB; int ldst; long long colG;
  if constexpr (EPI == 6) {
    const int cb = colBase >> 10;   // uniform per block (256-aligned within 1024 regions)
    dstB = (cb == 0 ? (bf16*)out : (cb == 1 ? (bf16*)out2 : (bf16*)out3));
    ldst = EMBED; colG = colBase & 1023;
  } else if constexpr (EPI == 5) {
    dstB = (bf16*)out + (long long)zb * sOz + (long long)kh * sOk;
    ldst = ldo; colG = colBase;
  } else {
    dstB = (bf16*)out; ldst = ldo; colG = colBase;
  }
  const int srow = tid >> 5, sc = tid & 31;
#pragma unroll
  for (int p = 0; p < 16; ++p) {
    const int row = p * 16 + srow;
    bf16x8 vrow = *(const bf16x8*)((const char*)ct + row * 512 + ((sc * 16) ^ (((row >> 2) & 3) << 5)));
    *(bf16x8*)(dstB + (long long)(rowBase + row) * ldst + colG + sc * 8) = vrow;
  }
}

// ---------------- row softmax: E bf16 [rows][SEQ] -> P bf16 ----------------
__global__ __launch_bounds__(256) void softmax_kernel(const bf16* __restrict__ E,
                                                      bf16* __restrict__ P) {
  const size_t row = blockIdx.x;
  const int t = threadIdx.x;
  bf16x8 ev = *(const bf16x8*)(E + row * SEQ + (size_t)t * 8);
  float e[8];
#pragma unroll
  for (int q = 0; q < 8; ++q) e[q] = (float)ev[q];
  float m = e[0];
#pragma unroll
  for (int q = 1; q < 8; ++q) m = fmaxf(m, e[q]);
#pragma unroll
  for (int o = 32; o; o >>= 1) m = fmaxf(m, __shfl_xor(m, o));
  __shared__ float red[8];
  const int w = t >> 6;
  if ((t & 63) == 0) red[w] = m;
  __syncthreads();
  m = fmaxf(fmaxf(red[0], red[1]), fmaxf(red[2], red[3]));
  float s = 0.f;
#pragma unroll
  for (int q = 0; q < 8; ++q) { e[q] = __expf(e[q] - m); s += e[q]; }
#pragma unroll
  for (int o = 32; o; o >>= 1) s += __shfl_xor(s, o);
  if ((t & 63) == 0) red[4 + w] = s;
  __syncthreads();
  s = red[4] + red[5] + red[6] + red[7];
  const float inv = 1.0f / s;
  bf16x8 pv;
#pragma unroll
  for (int q = 0; q < 8; ++q) pv[q] = (bf16)(e[q] * inv);
  *(bf16x8*)(P + row * SEQ + (size_t)t * 8) = pv;
}

// ---------------- LayerNorm: out = LN(Xb + X2b [+cb] + Rb) * g + b ----------------
__global__ __launch_bounds__(256) void ln_kernel(const bf16* __restrict__ Xb,
                                                 const bf16* __restrict__ X2b,
                                                 const bf16* __restrict__ Rb,
                                                 const float* __restrict__ cb,
                                                 const float* __restrict__ gm,
                                                 const float* __restrict__ bt,
                                                 float* __restrict__ of,
                                                 bf16* __restrict__ ob) {
  const size_t row = blockIdx.x;
  const int t = threadIdx.x;
  bf16x4 xv = *(const bf16x4*)(Xb + row * EMBED + (size_t)t * 4);
  bf16x4 rv = *(const bf16x4*)(Rb + row * EMBED + (size_t)t * 4);
  float4 v;
  v.x = (float)xv[0] + (float)rv[0];
  v.y = (float)xv[1] + (float)rv[1];
  v.z = (float)xv[2] + (float)rv[2];
  v.w = (float)xv[3] + (float)rv[3];
  if (X2b) {
    bf16x4 x2 = *(const bf16x4*)(X2b + row * EMBED + (size_t)t * 4);
    v.x += (float)x2[0]; v.y += (float)x2[1]; v.z += (float)x2[2]; v.w += (float)x2[3];
  }
  if (cb) {
    float4 c4 = ((const float4*)cb)[t];
    v.x += c4.x; v.y += c4.y; v.z += c4.z; v.w += c4.w;
  }
  float s  = v.x + v.y + v.z + v.w;
  float ss = v.x * v.x + v.y * v.y + v.z * v.z + v.w * v.w;
#pragma unroll
  for (int o = 32; o; o >>= 1) { s += __shfl_xor(s, o); ss += __shfl_xor(ss, o); }
  __shared__ float red[8];
  const int w = t >> 6;
  if ((t & 63) == 0) { red[w] = s; red[4 + w] = ss; }
  __syncthreads();
  s  = red[0] + red[1] + red[2] + red[3];
  ss = red[4] + red[5] + red[6] + red[7];
  const float mu  = s * (1.0f / EMBED);
  const float inv = rsqrtf(ss * (1.0f / EMBED) - mu * mu + 1e-5f);
  float4 gv = ((const float4*)gm)[t];
  float4 bv = ((const float4*)bt)[t];
  float4 o4;
  o4.x = (v.x - mu) * inv * gv.x + bv.x;
  o4.y = (v.y - mu) * inv * gv.y + bv.y;
  o4.z = (v.z - mu) * inv * gv.z + bv.z;
  o4.w = (v.w - mu) * inv * gv.w + bv.w;
  if (of) ((float4*)(of + row * EMBED))[t] = o4;
  if (ob) {
    bf16x4 p;
    p[0] = (bf16)o4.x; p[1] = (bf16)o4.y; p[2] = (bf16)o4.z; p[3] = (bf16)o4.w;
    *(bf16x4*)(ob + row * EMBED + (size_t)t * 4) = p;
  }
}

// ---------------- launch ----------------
extern "C" void kernel_launch(void* const* d_in, const int* in_sizes, int n_in,
                              void* d_out, int out_size, void* d_ws, size_t ws_size,
                              hipStream_t stream) {
  const float* x   = (const float*)d_in[0];
  const float* Wq  = (const float*)d_in[1];
  const float* bq  = (const float*)d_in[2];
  const float* Wk  = (const float*)d_in[3];
  const float* bk  = (const float*)d_in[4];
  const float* Wv  = (const float*)d_in[5];
  const float* bv  = (const float*)d_in[6];
  const float* W1  = (const float*)d_in[7];
  const float* b1  = (const float*)d_in[8];
  const float* W2  = (const float*)d_in[9];
  const float* b2  = (const float*)d_in[10];
  const float* g1  = (const float*)d_in[11];
  const float* be1 = (const float*)d_in[12];
  const float* g2  = (const float*)d_in[13];
  const float* be2 = (const float*)d_in[14];
  float* out = (float*)d_out;
  char* ws = (char*)d_ws;

  bf16*  hb   = (bf16*)(ws + OFF_HB);
  bf16*  xpeb = (bf16*)(ws + OFF_XPE_B);
  bf16*  Qb   = (bf16*)(ws + OFF_Q);
  bf16*  Kb   = (bf16*)(ws + OFF_K);
  bf16*  VT   = (bf16*)(ws + OFF_VT);
  bf16*  Vb   = (bf16*)(ws + OFF_ATTN);   // row-major V (dead after vtrans)
  bf16*  E    = (bf16*)(ws + OFF_E);      // 32MB bf16
  bf16*  P    = (bf16*)(ws + OFF_Q);      // reuse Q+K region after QK^T
  bf16*  pv0  = (bf16*)(ws + OFF_ATTN);   // PV part 0 (Vb dead)
  bf16*  pv1  = (bf16*)(ws + OFF_E);      // PV part 1 (E dead after softmax)
  bf16*  T1   = (bf16*)(ws + OFF_E);      // FF1 out (pv1 dead after LN1)
  bf16*  ff0  = (bf16*)(ws + OFF_ATTN);   // FF2 part 0 (pv0 dead)
  bf16*  ff1  = (bf16*)(ws + OFF_Q);      // FF2 part 1 (P dead)
  bf16*  WqkvT = (bf16*)(ws + OFF_WQKVT);
  bf16*  W1T  = (bf16*)(ws + OFF_W1T);
  bf16*  W2T  = (bf16*)(ws + OFF_W2T);

  // signed bf16-element offsets between split-K output halves
  const long long sOk_pv = ((long long)OFF_E - (long long)OFF_ATTN) / 2;   // pv1 - pv0
  const long long sOk_ff = ((long long)OFF_Q - (long long)OFF_ATTN) / 2;   // ff1 - ff0

  const dim3 tb(32, 8);
  transpose_kernel<<<dim3(EMBED / 32, EMBED / 32), tb, 0, stream>>>(Wq, WqkvT, EMBED, EMBED);
  transpose_kernel<<<dim3(EMBED / 32, EMBED / 32), tb, 0, stream>>>(Wk, WqkvT + (size_t)EMBED * EMBED, EMBED, EMBED);
  transpose_kernel<<<dim3(EMBED / 32, EMBED / 32), tb, 0, stream>>>(Wv, WqkvT + 2ull * EMBED * EMBED, EMBED, EMBED);
  transpose_kernel<<<dim3(FFDIM / 32, EMBED / 32), tb, 0, stream>>>(W1, W1T, EMBED, FFDIM);
  transpose_kernel<<<dim3(EMBED / 32, FFDIM / 32), tb, 0, stream>>>(W2, W2T, FFDIM, EMBED);

  pe_add_kernel<<<(SEQ * 512) / 256, 256, 0, stream>>>(x, xpeb);

  // fused QKV, all row-major (384 blocks)
  gemm8_kernel<6><<<dim3(3072 / BNX, MTOK / BMX, 1), 512, 0, stream>>>(
      xpeb, WqkvT, bq, Qb, EMBED, EMBED, EMBED, EMBED, 1,
      0, 0, 0, 0, 0, 0, 1.0f, bk, bv, Kb, Vb);

  // V -> VT (coalesced LDS transpose)
  vtrans_kernel<<<dim3(EMBED / 32, SEQ / 32, BATCH), tb, 0, stream>>>(Vb, VT);

  // QK^T: E = bf16(Q @ K^T / 32)  (256 blocks)
  gemm8_kernel<5><<<dim3(SEQ / BNX, SEQ / BMX, BATCH), 512, 0, stream>>>(
      Qb, Kb, nullptr, E, EMBED, EMBED, EMBED, SEQ, BATCH,
      (long long)SEQ * EMBED, (long long)SEQ * EMBED, (long long)SEQ * SEQ,
      0, 0, 0, 0.03125f, nullptr, nullptr, nullptr, nullptr);

  softmax_kernel<<<BATCH * SEQ, 256, 0, stream>>>(E, P);

  // PV split-K: K=2048 -> 2x1024, bf16 partials (256 blocks)
  gemm8_kernel<5><<<dim3(EMBED / BNX, SEQ / BMX, BATCH * 2), 512, 0, stream>>>(
      P, VT, nullptr, pv0, 1024, SEQ, SEQ, EMBED, BATCH,
      (long long)SEQ * SEQ, (long long)EMBED * SEQ, (long long)SEQ * EMBED,
      1024, 1024, sOk_pv,
      1.0f, nullptr, nullptr, nullptr, nullptr);

  // hb = bf16(LN(pv0 + pv1 + xpeb))
  ln_kernel<<<MTOK, 256, 0, stream>>>(pv0, pv1, xpeb, nullptr, g1, be1, nullptr, hb);

  // FF1: relu(hb @ W1 + b1)  (512 blocks)
  gemm8_kernel<3><<<dim3(FFDIM / BNX, MTOK / BMX, 1), 512, 0, stream>>>(
      hb, W1T, b1, T1, EMBED, EMBED, EMBED, FFDIM, 1,
      0, 0, 0, 0, 0, 0, 1.0f, nullptr, nullptr, nullptr, nullptr);

  // FF2 split-K: K=4096 -> 2x2048, bf16 partials (256 blocks); bias folded into LN2
  gemm8_kernel<5><<<dim3(EMBED / BNX, MTOK / BMX, 2), 512, 0, stream>>>(
      T1, W2T, nullptr, ff0, 2048, FFDIM, FFDIM, EMBED, 1,
      0, 0, 0,
      2048, 2048, sOk_ff,
      1.0f, nullptr, nullptr, nullptr, nullptr);

  // out = LN(ff0 + ff1 + b2 + hb)
  ln_kernel<<<MTOK, 256, 0, stream>>>(ff0, ff1, hb, b2, g2, be2, out, nullptr);
}

// Round 15
// 331.217 us; speedup vs baseline: 1.3179x; 1.0018x over previous
//
#include <hip/hip_runtime.h>
#include <hip/hip_bf16.h>
#include <cmath>
#include <cstdint>

typedef __bf16 bf16;
typedef __bf16 bf16x8 __attribute__((ext_vector_type(8)));
typedef __bf16 bf16x4 __attribute__((ext_vector_type(4)));
typedef float  f32x4  __attribute__((ext_vector_type(4)));

#define EMBED 1024
#define FFDIM 4096
#define BATCH 4
#define SEQ   2048
#define MTOK  (BATCH*SEQ)

// ---------------- workspace layout ----------------
static constexpr size_t OFF_HB    = 0;              // 16MB bf16 hb (LN1 w; FF1,LN2 r)
static constexpr size_t OFF_XPE_B = 32ull << 20;    // 16MB bf16 xpeb (PE w; QKV,LN1 r)
static constexpr size_t OFF_Q     = 48ull << 20;    // Qb 16MB; then P 32MB (48-80); then ff1 bf16
static constexpr size_t OFF_K     = 64ull << 20;
static constexpr size_t OFF_VT    = 80ull << 20;    // 16MB bf16 [4][1024][2048]
static constexpr size_t OFF_E     = 96ull << 20;    // E bf16 32MB; then pv1 bf16; then T1 bf16 64MB
static constexpr size_t OFF_ATTN  = 160ull << 20;   // Vb 16MB; then pv0 bf16; then ff0 bf16
static constexpr size_t OFF_WQKVT = 224ull << 20;   // 6MB bf16 [3072][1024]
static constexpr size_t OFF_W1T   = 230ull << 20;   // 8MB
static constexpr size_t OFF_W2T   = 238ull << 20;   // 8MB

// ---------------- wait/barrier primitives ----------------
// r15: loosened intra-phase sync — no lgkm drain before MFMA (compiler emits
// fine-grained per-use lgkmcnt), no post-MFMA order pin. Barriers keep their
// sched_barrier guards; vmcnt waits keep pins (ledger ordering).
#define VMCNT6 { asm volatile("s_waitcnt vmcnt(6)" ::: "memory"); __builtin_amdgcn_sched_barrier(0); }
#define VMCNT8 { asm volatile("s_waitcnt vmcnt(8)" ::: "memory"); __builtin_amdgcn_sched_barrier(0); }
#define VMCNT0 { asm volatile("s_waitcnt vmcnt(0)" ::: "memory"); __builtin_amdgcn_sched_barrier(0); }
#define PH_BAR  { __builtin_amdgcn_sched_barrier(0); __builtin_amdgcn_s_barrier(); \
                  __builtin_amdgcn_sched_barrier(0); }
#define PH_END  { }
#define BARONLY { __builtin_amdgcn_sched_barrier(0); __builtin_amdgcn_s_barrier(); \
                  __builtin_amdgcn_sched_barrier(0); }

__device__ __forceinline__ void gload_lds16(const void* g, void* l) {
  __builtin_amdgcn_global_load_lds((const __attribute__((address_space(1))) void*)g,
                                   (__attribute__((address_space(3))) void*)l, 16, 0, 0);
}

// ---------------- PE add: xb = bf16(x + pe) ----------------
__global__ __launch_bounds__(256) void pe_add_kernel(const float* __restrict__ x,
                                                     bf16* __restrict__ xb) {
  int idx  = blockIdx.x * 256 + threadIdx.x;
  int pair = idx & 511;
  int s    = idx >> 9;
  float div = __expf((float)(2 * pair) * (-9.210340371976184f / (float)EMBED));
  float ang = (float)s * div;
  float sv = sinf(ang), cv = cosf(ang);
#pragma unroll
  for (int b = 0; b < BATCH; ++b) {
    size_t base = ((size_t)(b * SEQ + s)) * EMBED + (size_t)pair * 2;
    xb[base]     = (bf16)(x[base] + sv);
    xb[base + 1] = (bf16)(x[base + 1] + cv);
  }
}

// ---------------- weight transpose fp32[K][N] -> bf16[N][K] ----------------
__global__ __launch_bounds__(256) void transpose_kernel(const float* __restrict__ W,
                                                        bf16* __restrict__ Wt,
                                                        int K, int N) {
  __shared__ float tile[32][33];
  int nb = blockIdx.x * 32, kb = blockIdx.y * 32;
  int tx = threadIdx.x, ty = threadIdx.y;   // 32x8
#pragma unroll
  for (int i = 0; i < 32; i += 8)
    tile[ty + i][tx] = W[(size_t)(kb + ty + i) * N + nb + tx];
  __syncthreads();
#pragma unroll
  for (int i = 0; i < 32; i += 8)
    Wt[(size_t)(nb + ty + i) * K + kb + tx] = (bf16)tile[tx][ty + i];
}

// ---------------- V transpose bf16 [b][s][d] -> [b][d][s] ----------------
__global__ __launch_bounds__(256) void vtrans_kernel(const bf16* __restrict__ V,
                                                     bf16* __restrict__ VT) {
  __shared__ ushort tile[32][36];
  const int d0 = blockIdx.x * 32, s0 = blockIdx.y * 32, b = blockIdx.z;
  const ushort* src = (const ushort*)V + ((size_t)b * SEQ + s0) * EMBED + d0;
  ushort* dst = (ushort*)VT + ((size_t)b * EMBED + d0) * SEQ + s0;
  const int tx = threadIdx.x, ty = threadIdx.y;   // 32x8
#pragma unroll
  for (int i = 0; i < 32; i += 8)
    tile[ty + i][tx] = src[(size_t)(ty + i) * EMBED + tx];
  __syncthreads();
#pragma unroll
  for (int i = 0; i < 32; i += 8)
    dst[(size_t)(ty + i) * SEQ + tx] = tile[tx][ty + i];
}

// ---------------- gemm8: 256x256 tile, 8 waves (2Mx4N), 8-phase counted-vmcnt ----------------
// r14 epilogue (LDS-staged coalesced stores) + r15 loosened intra-phase sync.
// EPI 5: bf16 *scale (+batch +split-K)  EPI 3: bf16 +bias relu  EPI 6: fused QKV row-major +bias
#define BMX 256
#define BNX 256
#define BKX 64

#define MM16(QR, QC, FB) { \
  __builtin_amdgcn_s_setprio(1); \
  _Pragma("unroll") for (int kk = 0; kk < 2; ++kk) \
  _Pragma("unroll") for (int i2 = 0; i2 < 4; ++i2) \
  _Pragma("unroll") for (int j2 = 0; j2 < 2; ++j2) \
    acc[(QR)*4 + i2][(QC)*2 + j2] = __builtin_amdgcn_mfma_f32_16x16x32_bf16( \
        fa[kk][i2], FB[kk][j2], acc[(QR)*4 + i2][(QC)*2 + j2], 0, 0, 0); \
  __builtin_amdgcn_s_setprio(0); }

template <int EPI>
__global__ __launch_bounds__(512, 2) void gemm8_kernel(
    const bf16* __restrict__ A, const bf16* __restrict__ B,
    const float* __restrict__ bias, void* __restrict__ out,
    int K, int lda, int ldb, int ldo, int NB,
    long long sAz, long long sBz, long long sOz,
    long long sAk, long long sBk, long long sOk,
    float scale,
    const float* bias2, const float* bias3, void* out2, void* out3) {
  __shared__ __align__(16) char ldsbuf[131072];
  char* const ldsA = ldsbuf;            // 2buf x 32KB
  char* const ldsB = ldsbuf + 65536;    // 2buf x 32KB

  // T1: bijective XCD-chunked swizzle + grouped raster (G=8)
  const int gx = gridDim.x, gy = gridDim.y;
  int id = blockIdx.x + gx * (blockIdx.y + gy * blockIdx.z);
  const int nwg = gx * gy * gridDim.z;
  const int qd = nwg >> 3, rm = nwg & 7;
  const int xcd = id & 7, pos = id >> 3;
  const int lid = (xcd < rm ? xcd * (qd + 1) : rm * (qd + 1) + (xcd - rm) * qd) + pos;
  const int per = gx * gy;
  const int tz = lid / per;
  const int s2 = lid - tz * per;
  const int G = 8;
  const int ngrp = G * gy;
  const int grp = s2 / ngrp;
  const int within = s2 - grp * ngrp;
  const int gwf = gx - grp * G;
  const int gw = gwf < G ? gwf : G;
  const int tx = grp * G + within % gw;
  const int ty = within / gw;

  const int zb = tz % NB;
  const int kh = tz / NB;
  A += (long long)zb * sAz + (long long)kh * sAk;
  B += (long long)zb * sBz + (long long)kh * sBk;

  const int tid  = threadIdx.x;
  const int wave = tid >> 6;
  const int lane = tid & 63;
  const int wm = wave >> 2, wn = wave & 3;   // 2M x 4N
  const int rowBase = ty * BMX;
  const int colBase = tx * BNX;
  const int lr = lane & 15;
  const int g  = lane >> 4;
  const int lx = lr & 7;

  // staging: thread t -> rr = t>>3, slot (t&7)^(rr&7) (src pre-swizzled, rule 21)
  const int rr = tid >> 3;
  const int slot = (tid & 7) ^ (rr & 7);
  const bf16* Abase = A + (long long)(rowBase + rr) * lda + slot * 8;
  const bf16* Bb0 = B + (long long)(colBase + (rr & 31) + ((rr >> 5)) * 64) * ldb + slot * 8;
  const bf16* Bb1 = B + (long long)(colBase + (rr & 31) + (2 + (rr >> 5)) * 64) * ldb + slot * 8;

  auto stA = [&](int T, int bufOff, int qr) {
    char* dst = ldsA + bufOff + qr * 16384 + wave * 1024;
    const bf16* s = Abase + (long long)(qr * 64) * lda + (long long)T * BKX;
    gload_lds16(s, dst);
    gload_lds16(s + (long long)128 * lda, dst + 8192);
  };
  auto stB = [&](int T, int bufOff, int qc) {
    char* dst = ldsB + bufOff + qc * 16384 + wave * 1024;
    const long long off = (long long)(qc * 32) * ldb + (long long)T * BKX;
    gload_lds16(Bb0 + off, dst);
    gload_lds16(Bb1 + off, dst + 8192);
  };

  bf16x8 fa[2][4], fbq0[2][2], fbq1[2][2];
  auto rdFA = [&](int bufOff, int qr) {
    const char* base = ldsA + bufOff + qr * 16384 + wm * 8192;
#pragma unroll
    for (int kk = 0; kk < 2; ++kk) {
      const int sw = ((kk * 4 + g) ^ lx) << 4;
#pragma unroll
      for (int i2 = 0; i2 < 4; ++i2)
        fa[kk][i2] = *(const bf16x8*)(base + (i2 * 16 + lr) * 128 + sw);
    }
  };
  auto rdFB = [&](int bufOff, int qc, bf16x8 fb[2][2]) {
    const char* base = ldsB + bufOff + qc * 16384 + wn * 4096;
#pragma unroll
    for (int kk = 0; kk < 2; ++kk) {
      const int sw = ((kk * 4 + g) ^ lx) << 4;
#pragma unroll
      for (int j2 = 0; j2 < 2; ++j2)
        fb[kk][j2] = *(const bf16x8*)(base + (j2 * 16 + lr) * 128 + sw);
    }
  };

  const f32x4 zero4 = {0.f, 0.f, 0.f, 0.f};
  f32x4 acc[8][4];
#pragma unroll
  for (int i = 0; i < 8; ++i)
#pragma unroll
    for (int j = 0; j < 4; ++j) acc[i][j] = zero4;

  const int nK = K / BKX;   // even (>= 16) for all launches here

  // prologue: tile0 (4 halves) + tile1 hA0,hB0; drain tile0 (leave 4 in flight)
  stA(0, 0, 0); stB(0, 0, 0); stA(0, 0, 1); stB(0, 0, 1);
  stA(1, 32768, 0); stB(1, 32768, 0);
  { asm volatile("s_waitcnt vmcnt(4)" ::: "memory"); __builtin_amdgcn_sched_barrier(0); }
  __builtin_amdgcn_s_barrier(); __builtin_amdgcn_sched_barrier(0);

  // stage schedule (verified ledger r13):
  //   P1 hA1(T0+1) P2 hB1(T0+1) P3 hA0(T0+2) P4 hB0(T0+2)
  //   P5 hA1(T0+2) P6 hB1(T0+2) P7 hA0(T0+3) P8 hB0(T0+3)
#define STEP(STG) { \
    rdFA(0, 0); rdFB(0, 0, fbq0); stA(T0 + 1, 32768, 1);              /* P1 */ \
    VMCNT6; PH_BAR; MM16(0, 0, fbq0); PH_END; \
    rdFB(0, 1, fbq1); stB(T0 + 1, 32768, 1);                          /* P2 */ \
    PH_BAR; MM16(0, 1, fbq1); PH_END; \
    rdFA(0, 1); if (STG) stA(T0 + 2, 0, 0);                           /* P3 */ \
    PH_BAR; MM16(1, 0, fbq0); PH_END; \
    if (STG) stB(T0 + 2, 0, 0);                                       /* P4 */ \
    MM16(1, 1, fbq1); \
    if (STG) { VMCNT8 } else { VMCNT0 } \
    BARONLY; \
    rdFA(32768, 0); rdFB(32768, 0, fbq0); if (STG) stA(T0 + 2, 0, 1); /* P5 */ \
    VMCNT6; PH_BAR; MM16(0, 0, fbq0); PH_END; \
    rdFB(32768, 1, fbq1); if (STG) stB(T0 + 2, 0, 1);                 /* P6 */ \
    PH_BAR; MM16(0, 1, fbq1); PH_END; \
    rdFA(32768, 1); if (STG) stA(T0 + 3, 32768, 0);                   /* P7 */ \
    PH_BAR; MM16(1, 0, fbq0); PH_END; \
    if (STG) stB(T0 + 3, 32768, 0);                                   /* P8 */ \
    MM16(1, 1, fbq1); \
    if (STG) { VMCNT8 } \
    BARONLY; \
  }

  int T0 = 0;
  for (; T0 + 2 < nK; T0 += 2) STEP(1);
  STEP(0);
#undef STEP

  // ---- LDS-staged coalesced epilogue (r14, verified) ----
  bf16* ct = (bf16*)ldsbuf;   // [256][256] bf16 = 128KB
#pragma unroll
  for (int j = 0; j < 4; ++j) {
    const int lcol = wn * 64 + (j >> 1) * 32 + (j & 1) * 16 + lr;
    float bv = 0.f;
    if constexpr (EPI == 6) {
      const int gcol = colBase + lcol;
      const int c = gcol & 1023;
      const int cb = gcol >> 10;
      bv = (cb == 0 ? bias : (cb == 1 ? bias2 : bias3))[c];
    } else if constexpr (EPI == 3) {
      bv = bias[colBase + lcol];
    }
#pragma unroll
    for (int i = 0; i < 8; ++i) {
      const int lrow0 = wm * 128 + (i >> 2) * 64 + (i & 3) * 16 + g * 4;
#pragma unroll
      for (int rr2 = 0; rr2 < 4; ++rr2) {
        const int lrow = lrow0 + rr2;
        float v = acc[i][j][rr2];
        if constexpr (EPI == 5) v *= scale;
        else v += bv;
        if constexpr (EPI == 3) v = v > 0.f ? v : 0.f;
        ct[lrow * 256 + (lcol ^ (((lrow >> 2) & 3) << 4))] = (bf16)v;
      }
    }
  }
  __syncthreads();
  bf16* dstB; int ldst; long long colG;
  if constexpr (EPI == 6) {
    const int cb = colBase >> 10;
    dstB = (cb == 0 ? (bf16*)out : (cb == 1 ? (bf16*)out2 : (bf16*)out3));
    ldst = EMBED; colG = colBase & 1023;
  } else if constexpr (EPI == 5) {
    dstB = (bf16*)out + (long long)zb * sOz + (long long)kh * sOk;
    ldst = ldo; colG = colBase;
  } else {
    dstB = (bf16*)out; ldst = ldo; colG = colBase;
  }
  const int srow = tid >> 5, sc = tid & 31;
#pragma unroll
  for (int p = 0; p < 16; ++p) {
    const int row = p * 16 + srow;
    bf16x8 vrow = *(const bf16x8*)((const char*)ct + row * 512 + ((sc * 16) ^ (((row >> 2) & 3) << 5)));
    *(bf16x8*)(dstB + (long long)(rowBase + row) * ldst + colG + sc * 8) = vrow;
  }
}

// ---------------- row softmax: E bf16 [rows][SEQ] -> P bf16 ----------------
__global__ __launch_bounds__(256) void softmax_kernel(const bf16* __restrict__ E,
                                                      bf16* __restrict__ P) {
  const size_t row = blockIdx.x;
  const int t = threadIdx.x;
  bf16x8 ev = *(const bf16x8*)(E + row * SEQ + (size_t)t * 8);
  float e[8];
#pragma unroll
  for (int q = 0; q < 8; ++q) e[q] = (float)ev[q];
  float m = e[0];
#pragma unroll
  for (int q = 1; q < 8; ++q) m = fmaxf(m, e[q]);
#pragma unroll
  for (int o = 32; o; o >>= 1) m = fmaxf(m, __shfl_xor(m, o));
  __shared__ float red[8];
  const int w = t >> 6;
  if ((t & 63) == 0) red[w] = m;
  __syncthreads();
  m = fmaxf(fmaxf(red[0], red[1]), fmaxf(red[2], red[3]));
  float s = 0.f;
#pragma unroll
  for (int q = 0; q < 8; ++q) { e[q] = __expf(e[q] - m); s += e[q]; }
#pragma unroll
  for (int o = 32; o; o >>= 1) s += __shfl_xor(s, o);
  if ((t & 63) == 0) red[4 + w] = s;
  __syncthreads();
  s = red[4] + red[5] + red[6] + red[7];
  const float inv = 1.0f / s;
  bf16x8 pv;
#pragma unroll
  for (int q = 0; q < 8; ++q) pv[q] = (bf16)(e[q] * inv);
  *(bf16x8*)(P + row * SEQ + (size_t)t * 8) = pv;
}

// ---------------- LayerNorm: out = LN(Xb + X2b [+cb] + Rb) * g + b ----------------
__global__ __launch_bounds__(256) void ln_kernel(const bf16* __restrict__ Xb,
                                                 const bf16* __restrict__ X2b,
                                                 const bf16* __restrict__ Rb,
                                                 const float* __restrict__ cb,
                                                 const float* __restrict__ gm,
                                                 const float* __restrict__ bt,
                                                 float* __restrict__ of,
                                                 bf16* __restrict__ ob) {
  const size_t row = blockIdx.x;
  const int t = threadIdx.x;
  bf16x4 xv = *(const bf16x4*)(Xb + row * EMBED + (size_t)t * 4);
  bf16x4 rv = *(const bf16x4*)(Rb + row * EMBED + (size_t)t * 4);
  float4 v;
  v.x = (float)xv[0] + (float)rv[0];
  v.y = (float)xv[1] + (float)rv[1];
  v.z = (float)xv[2] + (float)rv[2];
  v.w = (float)xv[3] + (float)rv[3];
  if (X2b) {
    bf16x4 x2 = *(const bf16x4*)(X2b + row * EMBED + (size_t)t * 4);
    v.x += (float)x2[0]; v.y += (float)x2[1]; v.z += (float)x2[2]; v.w += (float)x2[3];
  }
  if (cb) {
    float4 c4 = ((const float4*)cb)[t];
    v.x += c4.x; v.y += c4.y; v.z += c4.z; v.w += c4.w;
  }
  float s  = v.x + v.y + v.z + v.w;
  float ss = v.x * v.x + v.y * v.y + v.z * v.z + v.w * v.w;
#pragma unroll
  for (int o = 32; o; o >>= 1) { s += __shfl_xor(s, o); ss += __shfl_xor(ss, o); }
  __shared__ float red[8];
  const int w = t >> 6;
  if ((t & 63) == 0) { red[w] = s; red[4 + w] = ss; }
  __syncthreads();
  s  = red[0] + red[1] + red[2] + red[3];
  ss = red[4] + red[5] + red[6] + red[7];
  const float mu  = s * (1.0f / EMBED);
  const float inv = rsqrtf(ss * (1.0f / EMBED) - mu * mu + 1e-5f);
  float4 gv = ((const float4*)gm)[t];
  float4 bv = ((const float4*)bt)[t];
  float4 o4;
  o4.x = (v.x - mu) * inv * gv.x + bv.x;
  o4.y = (v.y - mu) * inv * gv.y + bv.y;
  o4.z = (v.z - mu) * inv * gv.z + bv.z;
  o4.w = (v.w - mu) * inv * gv.w + bv.w;
  if (of) ((float4*)(of + row * EMBED))[t] = o4;
  if (ob) {
    bf16x4 p;
    p[0] = (bf16)o4.x; p[1] = (bf16)o4.y; p[2] = (bf16)o4.z; p[3] = (bf16)o4.w;
    *(bf16x4*)(ob + row * EMBED + (size_t)t * 4) = p;
  }
}

// ---------------- launch ----------------
extern "C" void kernel_launch(void* const* d_in, const int* in_sizes, int n_in,
                              void* d_out, int out_size, void* d_ws, size_t ws_size,
                              hipStream_t stream) {
  const float* x   = (const float*)d_in[0];
  const float* Wq  = (const float*)d_in[1];
  const float* bq  = (const float*)d_in[2];
  const float* Wk  = (const float*)d_in[3];
  const float* bk  = (const float*)d_in[4];
  const float* Wv  = (const float*)d_in[5];
  const float* bv  = (const float*)d_in[6];
  const float* W1  = (const float*)d_in[7];
  const float* b1  = (const float*)d_in[8];
  const float* W2  = (const float*)d_in[9];
  const float* b2  = (const float*)d_in[10];
  const float* g1  = (const float*)d_in[11];
  const float* be1 = (const float*)d_in[12];
  const float* g2  = (const float*)d_in[13];
  const float* be2 = (const float*)d_in[14];
  float* out = (float*)d_out;
  char* ws = (char*)d_ws;

  bf16*  hb   = (bf16*)(ws + OFF_HB);
  bf16*  xpeb = (bf16*)(ws + OFF_XPE_B);
  bf16*  Qb   = (bf16*)(ws + OFF_Q);
  bf16*  Kb   = (bf16*)(ws + OFF_K);
  bf16*  VT   = (bf16*)(ws + OFF_VT);
  bf16*  Vb   = (bf16*)(ws + OFF_ATTN);   // row-major V (dead after vtrans)
  bf16*  E    = (bf16*)(ws + OFF_E);      // 32MB bf16
  bf16*  P    = (bf16*)(ws + OFF_Q);      // reuse Q+K region after QK^T
  bf16*  pv0  = (bf16*)(ws + OFF_ATTN);   // PV part 0 (Vb dead)
  bf16*  pv1  = (bf16*)(ws + OFF_E);      // PV part 1 (E dead after softmax)
  bf16*  T1   = (bf16*)(ws + OFF_E);      // FF1 out (pv1 dead after LN1)
  bf16*  ff0  = (bf16*)(ws + OFF_ATTN);   // FF2 part 0 (pv0 dead)
  bf16*  ff1  = (bf16*)(ws + OFF_Q);      // FF2 part 1 (P dead)
  bf16*  WqkvT = (bf16*)(ws + OFF_WQKVT);
  bf16*  W1T  = (bf16*)(ws + OFF_W1T);
  bf16*  W2T  = (bf16*)(ws + OFF_W2T);

  const long long sOk_pv = ((long long)OFF_E - (long long)OFF_ATTN) / 2;   // pv1 - pv0
  const long long sOk_ff = ((long long)OFF_Q - (long long)OFF_ATTN) / 2;   // ff1 - ff0

  const dim3 tb(32, 8);
  transpose_kernel<<<dim3(EMBED / 32, EMBED / 32), tb, 0, stream>>>(Wq, WqkvT, EMBED, EMBED);
  transpose_kernel<<<dim3(EMBED / 32, EMBED / 32), tb, 0, stream>>>(Wk, WqkvT + (size_t)EMBED * EMBED, EMBED, EMBED);
  transpose_kernel<<<dim3(EMBED / 32, EMBED / 32), tb, 0, stream>>>(Wv, WqkvT + 2ull * EMBED * EMBED, EMBED, EMBED);
  transpose_kernel<<<dim3(FFDIM / 32, EMBED / 32), tb, 0, stream>>>(W1, W1T, EMBED, FFDIM);
  transpose_kernel<<<dim3(EMBED / 32, FFDIM / 32), tb, 0, stream>>>(W2, W2T, FFDIM, EMBED);

  pe_add_kernel<<<(SEQ * 512) / 256, 256, 0, stream>>>(x, xpeb);

  // fused QKV, all row-major (384 blocks)
  gemm8_kernel<6><<<dim3(3072 / BNX, MTOK / BMX, 1), 512, 0, stream>>>(
      xpeb, WqkvT, bq, Qb, EMBED, EMBED, EMBED, EMBED, 1,
      0, 0, 0, 0, 0, 0, 1.0f, bk, bv, Kb, Vb);

  // V -> VT (coalesced LDS transpose)
  vtrans_kernel<<<dim3(EMBED / 32, SEQ / 32, BATCH), tb, 0, stream>>>(Vb, VT);

  // QK^T: E = bf16(Q @ K^T / 32)  (256 blocks)
  gemm8_kernel<5><<<dim3(SEQ / BNX, SEQ / BMX, BATCH), 512, 0, stream>>>(
      Qb, Kb, nullptr, E, EMBED, EMBED, EMBED, SEQ, BATCH,
      (long long)SEQ * EMBED, (long long)SEQ * EMBED, (long long)SEQ * SEQ,
      0, 0, 0, 0.03125f, nullptr, nullptr, nullptr, nullptr);

  softmax_kernel<<<BATCH * SEQ, 256, 0, stream>>>(E, P);

  // PV split-K: K=2048 -> 2x1024, bf16 partials (256 blocks)
  gemm8_kernel<5><<<dim3(EMBED / BNX, SEQ / BMX, BATCH * 2), 512, 0, stream>>>(
      P, VT, nullptr, pv0, 1024, SEQ, SEQ, EMBED, BATCH,
      (long long)SEQ * SEQ, (long long)EMBED * SEQ, (long long)SEQ * EMBED,
      1024, 1024, sOk_pv,
      1.0f, nullptr, nullptr, nullptr, nullptr);

  // hb = bf16(LN(pv0 + pv1 + xpeb))
  ln_kernel<<<MTOK, 256, 0, stream>>>(pv0, pv1, xpeb, nullptr, g1, be1, nullptr, hb);

  // FF1: relu(hb @ W1 + b1)  (512 blocks)
  gemm8_kernel<3><<<dim3(FFDIM / BNX, MTOK / BMX, 1), 512, 0, stream>>>(
      hb, W1T, b1, T1, EMBED, EMBED, EMBED, FFDIM, 1,
      0, 0, 0, 0, 0, 0, 1.0f, nullptr, nullptr, nullptr, nullptr);

  // FF2 split-K: K=4096 -> 2x2048, bf16 partials (256 blocks); bias folded into LN2
  gemm8_kernel<5><<<dim3(EMBED / BNX, MTOK / BMX, 2), 512, 0, stream>>>(
      T1, W2T, nullptr, ff0, 2048, FFDIM, FFDIM, EMBED, 1,
      0, 0, 0,
      2048, 2048, sOk_ff,
      1.0f, nullptr, nullptr, nullptr, nullptr);

  // out = LN(ff0 + ff1 + b2 + hb)
  ln_kernel<<<MTOK, 256, 0, stream>>>(ff0, ff1, hb, b2, g2, be2, out, nullptr);
}